// Round 3
// baseline (992.432 us; speedup 1.0000x reference)
//
#include <hip/hip_runtime.h>

#define DEV __device__ __forceinline__

constexpr int NX = 64;   // state dim
constexpr int NU = 32;   // input dim
constexpr int NH = 32;   // horizon
constexpr int NB = 192;  // batch

// LDS strides (floats). All strides*4 are multiples of 16B for ld4.
constexpr int SP  = 68;  // P
constexpr int SG  = 64;  // G = P*A
constexpr int SV  = 36;  // V = P*B
constexpr int SXs = 36;  // Qxu (x-major)
constexpr int SQs = 36;  // Quu / Quu^{-1}
constexpr int SK  = 68;  // K

// workspace layout (float offsets) — consumed by k_solve
constexpr int WS_P   = 0;                          // [NH+1][64*64]  P_s (slots 1..32)
constexpr int WS_QI  = WS_P  + (NH + 1) * NX * NX; // [NH][32*32]    Quu^{-1} row-major
constexpr int WS_QXU = WS_QI + NH * NU * NU;       // [NH][64*32]    Qxu row-major (x,u)
constexpr int WS_K   = WS_QXU + NH * NX * NU;      // [NH][32*64]    K row-major (u,x)

DEV float4 ld4(const float* p) { return *reinterpret_cast<const float4*>(p); }
DEV void   st4(float* p, float4 v) { *reinterpret_cast<float4*>(p) = v; }
DEV float  dot4(float4 a, float4 b) {
  return fmaf(a.x, b.x, fmaf(a.y, b.y, fmaf(a.z, b.z, a.w * b.w)));
}
DEV void fma4(float4& a, float s, float4 b) {
  a.x = fmaf(s, b.x, a.x); a.y = fmaf(s, b.y, a.y);
  a.z = fmaf(s, b.z, a.z); a.w = fmaf(s, b.w, a.w);
}
DEV void fma8(float* acc, float s, float4 b0, float4 b1) {
  acc[0] = fmaf(s, b0.x, acc[0]); acc[1] = fmaf(s, b0.y, acc[1]);
  acc[2] = fmaf(s, b0.z, acc[2]); acc[3] = fmaf(s, b0.w, acc[3]);
  acc[4] = fmaf(s, b1.x, acc[4]); acc[5] = fmaf(s, b1.y, acc[5]);
  acc[6] = fmaf(s, b1.z, acc[6]); acc[7] = fmaf(s, b1.w, acc[7]);
}

// ---------------------------------------------------------------------------
// Kernel 1: batch-independent Riccati matrix recursion. 1 block, 1024 threads
// (16 waves, 4/SIMD). Wave-slab register-tiled GEMM phases; shared operands
// via same-address LDS b128 broadcasts; lane operands full-width coalesced.
// 5 barriers/stage, no symmetrize phase.
// ---------------------------------------------------------------------------
__global__ __launch_bounds__(1024, 4) void k_riccati_mats(
    const float* __restrict__ Ag, const float* __restrict__ Bg,
    const float* __restrict__ Qxg, const float* __restrict__ Rug,
    const float* __restrict__ Qfg, float* __restrict__ ws) {
  __shared__ __align__(16) float sP[NX * SP];   // 17408 B  P_{s+1} -> Qxx -> P_s
  __shared__ __align__(16) float sG[NX * SG];   // 16384 B  G = P*A
  __shared__ __align__(16) float sVK[NX * SV];  //  9216 B  V = P*B ; later K (32*68)
  __shared__ __align__(16) float sX[NX * SXs];  //  9216 B  Qxu (x-major)
  __shared__ __align__(16) float sQ[NU * SQs];  //  4608 B  Quu -> Quu^{-1}
  float* sV = sVK;
  float* sK = sVK;  // alias: V dead after Ph2; K written Ph4, read Ph5

  const int t    = threadIdx.x;
  const int lane = t & 63;
  const int wv   = t >> 6;   // 0..15

  float* gP   = ws + WS_P;
  float* gQI  = ws + WS_QI;
  float* gQxu = ws + WS_QXU;
  float* gK   = ws + WS_K;

  // init sP = Qf
  {
    const int i = t >> 4, j0 = (t & 15) * 4;
    st4(sP + i * SP + j0, ld4(Qfg + i * NX + j0));
  }
  __syncthreads();

  for (int s = NH - 1; s >= 0; --s) {
    // ---- Ph1: gP store + [G|V] = P * [A|B]
    {
      const int i0 = wv * 4, j = lane, jb = lane & 31;
      float* gPs = gP + (s + 1) * NX * NX;
#pragma unroll
      for (int r = 0; r < 4; ++r) gPs[(i0 + r) * NX + j] = sP[(i0 + r) * SP + j];

      float g0 = 0, g1 = 0, g2 = 0, g3 = 0, v0 = 0, v1 = 0, v2 = 0, v3 = 0;
#pragma unroll 2
      for (int k0 = 0; k0 < NX; k0 += 4) {
        const float4 p0 = ld4(sP + (i0 + 0) * SP + k0);  // broadcast reads
        const float4 p1 = ld4(sP + (i0 + 1) * SP + k0);
        const float4 p2 = ld4(sP + (i0 + 2) * SP + k0);
        const float4 p3 = ld4(sP + (i0 + 3) * SP + k0);
        const float a0 = Ag[(k0 + 0) * NX + j], a1 = Ag[(k0 + 1) * NX + j];
        const float a2 = Ag[(k0 + 2) * NX + j], a3 = Ag[(k0 + 3) * NX + j];
        const float b0 = Bg[(k0 + 0) * NU + jb], b1 = Bg[(k0 + 1) * NU + jb];
        const float b2 = Bg[(k0 + 2) * NU + jb], b3 = Bg[(k0 + 3) * NU + jb];
        g0 = fmaf(p0.x, a0, g0); g0 = fmaf(p0.y, a1, g0); g0 = fmaf(p0.z, a2, g0); g0 = fmaf(p0.w, a3, g0);
        g1 = fmaf(p1.x, a0, g1); g1 = fmaf(p1.y, a1, g1); g1 = fmaf(p1.z, a2, g1); g1 = fmaf(p1.w, a3, g1);
        g2 = fmaf(p2.x, a0, g2); g2 = fmaf(p2.y, a1, g2); g2 = fmaf(p2.z, a2, g2); g2 = fmaf(p2.w, a3, g2);
        g3 = fmaf(p3.x, a0, g3); g3 = fmaf(p3.y, a1, g3); g3 = fmaf(p3.z, a2, g3); g3 = fmaf(p3.w, a3, g3);
        v0 = fmaf(p0.x, b0, v0); v0 = fmaf(p0.y, b1, v0); v0 = fmaf(p0.z, b2, v0); v0 = fmaf(p0.w, b3, v0);
        v1 = fmaf(p1.x, b0, v1); v1 = fmaf(p1.y, b1, v1); v1 = fmaf(p1.z, b2, v1); v1 = fmaf(p1.w, b3, v1);
        v2 = fmaf(p2.x, b0, v2); v2 = fmaf(p2.y, b1, v2); v2 = fmaf(p2.z, b2, v2); v2 = fmaf(p2.w, b3, v2);
        v3 = fmaf(p3.x, b0, v3); v3 = fmaf(p3.y, b1, v3); v3 = fmaf(p3.z, b2, v3); v3 = fmaf(p3.w, b3, v3);
      }
      sG[(i0 + 0) * SG + j] = g0; sG[(i0 + 1) * SG + j] = g1;
      sG[(i0 + 2) * SG + j] = g2; sG[(i0 + 3) * SG + j] = g3;
      if (j < 32) {
        sV[(i0 + 0) * SV + j] = v0; sV[(i0 + 1) * SV + j] = v1;
        sV[(i0 + 2) * SV + j] = v2; sV[(i0 + 3) * SV + j] = v3;
      }
    }
    __syncthreads();

    // ---- Ph2: Qxx = Qx + A^T G -> sP (waves 0-7) ;
    //           Quu = Ru + B^T V -> sQ (waves 8-11) ;
    //           Qxu = A^T V -> sX (waves 12-15)
    if (wv < 8) {
      const int a0 = wv * 8, b = lane;
      float acc[8];
#pragma unroll
      for (int r = 0; r < 8; ++r) acc[r] = Qxg[(a0 + r) * NX + b];
#pragma unroll 4
      for (int i = 0; i < NX; ++i) {
        const float4 aa0 = ld4(Ag + i * NX + a0);      // broadcast (1 L1 line)
        const float4 aa1 = ld4(Ag + i * NX + a0 + 4);
        const float gv = sG[i * SG + b];               // full-width coalesced
        fma8(acc, gv, aa0, aa1);
      }
#pragma unroll
      for (int r = 0; r < 8; ++r) sP[(a0 + r) * SP + b] = acc[r];
    } else if (wv < 12) {
      const int n = lane & 31, mh = lane >> 5;
      const int m0 = (wv - 8) * 8 + mh * 4;
      float4 acc;
      acc.x = Rug[(m0 + 0) * NU + n]; acc.y = Rug[(m0 + 1) * NU + n];
      acc.z = Rug[(m0 + 2) * NU + n]; acc.w = Rug[(m0 + 3) * NU + n];
#pragma unroll 4
      for (int i = 0; i < NX; ++i) {
        const float4 bb = ld4(Bg + i * NU + m0);
        const float vv = sV[i * SV + n];
        acc.x = fmaf(bb.x, vv, acc.x); acc.y = fmaf(bb.y, vv, acc.y);
        acc.z = fmaf(bb.z, vv, acc.z); acc.w = fmaf(bb.w, vv, acc.w);
      }
      sQ[(m0 + 0) * SQs + n] = acc.x; sQ[(m0 + 1) * SQs + n] = acc.y;
      sQ[(m0 + 2) * SQs + n] = acc.z; sQ[(m0 + 3) * SQs + n] = acc.w;
    } else {
      const int m = lane & 31, ah = lane >> 5;
      const int a0 = (wv - 12) * 16 + ah * 8;
      float acc[8] = {0, 0, 0, 0, 0, 0, 0, 0};
#pragma unroll 4
      for (int i = 0; i < NX; ++i) {
        const float4 aa0 = ld4(Ag + i * NX + a0);
        const float4 aa1 = ld4(Ag + i * NX + a0 + 4);
        const float vv = sV[i * SV + m];
        fma8(acc, vv, aa0, aa1);
      }
#pragma unroll
      for (int r = 0; r < 8; ++r) sX[(a0 + r) * SXs + m] = acc[r];
    }
    __syncthreads();

    // ---- Ph3: wave 0: register GJ inverse of Quu ; others: gQxu store
    if (t < 64) {
      const int i = t & 31, h = t >> 5;   // row, col-half
      float W[16];
#pragma unroll
      for (int r = 0; r < 16; ++r) W[r] = sQ[i * SQs + h * 16 + r];
#pragma unroll
      for (int j = 0; j < NU; ++j) {
        const int jh = j >> 4, jr = j & 15;
        const float d = __shfl(W[jr], j | (jh << 5));
        const float pinv = 1.0f / d;
        const float f = __shfl(W[jr], i | (jh << 5));
        float pr[16];
#pragma unroll
        for (int r = 0; r < 16; ++r) pr[r] = __shfl(W[r], j | (h << 5));
        float nw[16];
        if (i == j) {
#pragma unroll
          for (int r = 0; r < 16; ++r) nw[r] = pr[r] * pinv;
          if (h == jh) nw[jr] = pinv;
        } else {
          const float g = f * pinv;
#pragma unroll
          for (int r = 0; r < 16; ++r) nw[r] = fmaf(-g, pr[r], W[r]);
          if (h == jh) nw[jr] = -g;
        }
#pragma unroll
        for (int r = 0; r < 16; ++r) W[r] = nw[r];
      }
#pragma unroll
      for (int r = 0; r < 16; ++r) {
        sQ[i * SQs + h * 16 + r] = W[r];
        gQI[s * NU * NU + i * NU + h * 16 + r] = W[r];
      }
    } else {
      const int idx = t - 64;
      if (idx < 512) {
        const int i = idx >> 3, m0 = (idx & 7) * 4;
        st4(gQxu + s * NX * NU + i * NU + m0, ld4(sX + i * SXs + m0));
      }
    }
    __syncthreads();

    // ---- Ph4: K(m,j) = -sum_n Qinv(m,n) * Qxu(j,n)
    {
      const int m = lane & 31, c2 = lane >> 5;
      const int jA = wv * 4 + c2 * 2, jB = jA + 1;
      float accA = 0, accB = 0;
#pragma unroll
      for (int n0 = 0; n0 < NU; n0 += 4) {
        const float4 qiv = ld4(sQ + m * SQs + n0);
        const float4 xA = ld4(sX + jA * SXs + n0);   // 2 distinct addrs / wave
        const float4 xB = ld4(sX + jB * SXs + n0);
        accA += dot4(qiv, xA);
        accB += dot4(qiv, xB);
      }
      sK[m * SK + jA] = -accA;
      sK[m * SK + jB] = -accB;
    }
    __syncthreads();

    // ---- Ph5: gK store ; P' = Qxx + Qxu * K  (into sP)
    {
      const int m0 = wv * 2;
      gK[s * NU * NX + (m0 + 0) * NX + lane] = sK[(m0 + 0) * SK + lane];
      gK[s * NU * NX + (m0 + 1) * NX + lane] = sK[(m0 + 1) * SK + lane];

      const int i0 = wv * 4, j = lane;
      float acc[4];
#pragma unroll
      for (int r = 0; r < 4; ++r) acc[r] = sP[(i0 + r) * SP + j];
#pragma unroll
      for (int mm = 0; mm < NU; mm += 4) {
        float4 kk;
        kk.x = sK[(mm + 0) * SK + j]; kk.y = sK[(mm + 1) * SK + j];
        kk.z = sK[(mm + 2) * SK + j]; kk.w = sK[(mm + 3) * SK + j];
#pragma unroll
        for (int r = 0; r < 4; ++r) {
          const float4 xb = ld4(sX + (i0 + r) * SXs + mm);  // broadcast
          acc[r] += dot4(xb, kk);
        }
      }
#pragma unroll
      for (int r = 0; r < 4; ++r) sP[(i0 + r) * SP + j] = acc[r];
    }
    __syncthreads();
  }
}

// ---------------------------------------------------------------------------
// Kernel 2: per-batch KKT residuals (256 thr, parallel) + wave-0-only
// backward/forward recursion (no barriers, wave-synchronous LDS). Unchanged.
// ---------------------------------------------------------------------------
__global__ __launch_bounds__(256) void k_solve(
    const float* __restrict__ x0g, const float* __restrict__ xg,
    const float* __restrict__ ug, const float* __restrict__ lg,
    const float* __restrict__ Ag, const float* __restrict__ Bg,
    const float* __restrict__ Qxg, const float* __restrict__ Rug,
    const float* __restrict__ Qfg, const float* __restrict__ ws,
    float* __restrict__ outp) {
  const int b = blockIdx.x;
  const int t = threadIdx.x;

  const float* gP   = ws + WS_P;
  const float* gQI  = ws + WS_QI;
  const float* gQxu = ws + WS_QXU;
  const float* gK   = ws + WS_K;

  __shared__ __align__(16) float buf[11584];   // 46336 B
  float* sx   = buf;            // 2112  (dead after residuals)
  float* sl   = buf + 2112;     // 2112  (dead after residuals)
  float* su   = buf + 4224;     // 1024  (dead after residuals)
  float* sAT  = buf;            // overlay: 64*68 A^T padded, staged late
  float* xres = buf + 5248;     // 2048
  float* lxs  = buf + 7296;     // 2048
  float* lus  = buf + 9344;     // 1024
  float* kv   = buf + 10368;    // 1024
  float* swv  = buf + 11392;    // 64
  float* sqv  = buf + 11456;    // 32
  float* sduv = buf + 11488;    // 32
  float* sdxv = buf + 11520;    // 64

  for (int idx = t; idx < (NH + 1) * NX; idx += 256) {
    const int s = idx >> 6, i = idx & 63;
    sx[idx] = xg[(s * NB + b) * NX + i];
    sl[idx] = lg[(s * NB + b) * NX + i];
  }
  for (int idx = t; idx < NH * NU; idx += 256) {
    const int s = idx >> 5, j = idx & 31;
    su[idx] = ug[(s * NB + b) * NU + j];
  }
  __syncthreads();

  {
    const int s = t >> 3, i0 = (t & 7) * 8;
    float accx[8], accl[8];
#pragma unroll
    for (int ii = 0; ii < 8; ++ii) {
      accx[ii] = -sx[(s + 1) * NX + i0 + ii];
      accl[ii] = -sl[s * NX + i0 + ii];
    }
#pragma unroll 2
    for (int k0 = 0; k0 < NX; k0 += 4) {
      const float4 xv = ld4(sx + s * NX + k0);
#pragma unroll
      for (int ii = 0; ii < 8; ++ii) {
        accx[ii] += dot4(ld4(Ag + (i0 + ii) * NX + k0), xv);
        accl[ii] += dot4(ld4(Qxg + (i0 + ii) * NX + k0), xv);
      }
    }
#pragma unroll 2
    for (int k0 = 0; k0 < NU; k0 += 4) {
      const float4 uv = ld4(su + s * NU + k0);
#pragma unroll
      for (int ii = 0; ii < 8; ++ii)
        accx[ii] += dot4(ld4(Bg + (i0 + ii) * NU + k0), uv);
    }
#pragma unroll 4
    for (int k = 0; k < NX; ++k) {
      const float lv = sl[(s + 1) * NX + k];
      fma8(accl, lv, ld4(Ag + k * NX + i0), ld4(Ag + k * NX + i0 + 4));
    }
#pragma unroll
    for (int ii = 0; ii < 8; ++ii) {
      xres[s * NX + i0 + ii] = accx[ii];
      lxs[s * NX + i0 + ii] = accl[ii];
    }
  }
  {
    const int s = t >> 3, j0 = (t & 7) * 4;
    float4 acc = {0, 0, 0, 0};
#pragma unroll 2
    for (int k0 = 0; k0 < NU; k0 += 4) {
      const float4 uv = ld4(su + s * NU + k0);
      acc.x += dot4(ld4(Rug + (j0 + 0) * NU + k0), uv);
      acc.y += dot4(ld4(Rug + (j0 + 1) * NU + k0), uv);
      acc.z += dot4(ld4(Rug + (j0 + 2) * NU + k0), uv);
      acc.w += dot4(ld4(Rug + (j0 + 3) * NU + k0), uv);
    }
#pragma unroll 4
    for (int k = 0; k < NX; ++k) {
      const float lv = sl[(s + 1) * NX + k];
      fma4(acc, lv, ld4(Bg + k * NU + j0));
    }
    lus[s * NU + j0 + 0] = acc.x; lus[s * NU + j0 + 1] = acc.y;
    lus[s * NU + j0 + 2] = acc.z; lus[s * NU + j0 + 3] = acc.w;
  }
  __syncthreads();

  float p_i = 0.0f, dx_i = 0.0f;
  if (t < 64) {
    const int i = t;
    float acc = -sl[NH * NX + i];
#pragma unroll 4
    for (int k0 = 0; k0 < NX; k0 += 4)
      acc += dot4(ld4(Qfg + i * NX + k0), ld4(sx + NH * NX + k0));
    p_i = acc;
    dx_i = x0g[b * NX + i] - sx[i];
  }
  __syncthreads();

  for (int idx = t; idx < NX * NX / 4; idx += 256) {
    const int k = idx >> 4, i4 = (idx & 15) * 4;
    const float4 a4 = ld4(Ag + k * NX + i4);
    sAT[(i4 + 0) * SP + k] = a4.x;
    sAT[(i4 + 1) * SP + k] = a4.y;
    sAT[(i4 + 2) * SP + k] = a4.z;
    sAT[(i4 + 3) * SP + k] = a4.w;
  }
  __syncthreads();

  if (t >= 64) return;

  const int i = t;
  const int j = t & 31;
  const int hh = t >> 5;

  for (int s = NH - 1; s >= 0; --s) {
    const float* Pr = gP + (s + 1) * NX * NX + i * NX;
    const float* xr = xres + s * NX;
    float w = p_i;
#pragma unroll
    for (int k0 = 0; k0 < NX; k0 += 16) {
      w += dot4(ld4(Pr + k0),      ld4(xr + k0));
      w += dot4(ld4(Pr + k0 + 4),  ld4(xr + k0 + 4));
      w += dot4(ld4(Pr + k0 + 8),  ld4(xr + k0 + 8));
      w += dot4(ld4(Pr + k0 + 12), ld4(xr + k0 + 12));
    }
    swv[i] = w;

    float qx = lxs[s * NX + i];
#pragma unroll
    for (int k0 = 0; k0 < NX; k0 += 16) {
      qx += dot4(ld4(sAT + i * SP + k0),      ld4(swv + k0));
      qx += dot4(ld4(sAT + i * SP + k0 + 4),  ld4(swv + k0 + 4));
      qx += dot4(ld4(sAT + i * SP + k0 + 8),  ld4(swv + k0 + 8));
      qx += dot4(ld4(sAT + i * SP + k0 + 12), ld4(swv + k0 + 12));
    }

    float qa = 0.0f;
    const int kb = hh * 32;
#pragma unroll 8
    for (int kk = 0; kk < 32; ++kk)
      qa = fmaf(Bg[(kb + kk) * NU + j], swv[kb + kk], qa);
    qa += __shfl_xor(qa, 32);
    const float qu = qa + lus[s * NU + j];
    if (hh == 0) sqv[j] = qu;

    const float* Qr = gQI + s * NU * NU + j * NU + hh * 16;
    float ka = dot4(ld4(Qr),      ld4(sqv + hh * 16))
             + dot4(ld4(Qr + 4),  ld4(sqv + hh * 16 + 4))
             + dot4(ld4(Qr + 8),  ld4(sqv + hh * 16 + 8))
             + dot4(ld4(Qr + 12), ld4(sqv + hh * 16 + 12));
    ka += __shfl_xor(ka, 32);
    if (hh == 0) kv[s * NU + j] = -ka;

    const float* Xr = gQxu + s * NX * NU + i * NU;
    float pp = qx;
#pragma unroll
    for (int m0 = 0; m0 < NU; m0 += 4)
      pp += dot4(ld4(Xr + m0), ld4(kv + s * NU + m0));
    p_i = pp;
  }

  sdxv[i] = dx_i;
  for (int s = 0; s < NH; ++s) {
    const float* Kr = gK + s * NU * NX + j * NX + hh * 32;
    const float* dxh = sdxv + hh * 32;
    float da = 0.0f;
#pragma unroll
    for (int k0 = 0; k0 < 32; k0 += 16) {
      da += dot4(ld4(Kr + k0),      ld4(dxh + k0));
      da += dot4(ld4(Kr + k0 + 4),  ld4(dxh + k0 + 4));
      da += dot4(ld4(Kr + k0 + 8),  ld4(dxh + k0 + 8));
      da += dot4(ld4(Kr + k0 + 12), ld4(dxh + k0 + 12));
    }
    da += __shfl_xor(da, 32);
    const float du = da + kv[s * NU + j];
    if (hh == 0) {
      const int gi = (s * NB + b) * NU + j;
      outp[gi] = ug[gi] + du;
      sduv[j] = du;
    }

    float nxv = xres[s * NX + i];
    const float* Ar = Ag + i * NX;
#pragma unroll
    for (int k0 = 0; k0 < NX; k0 += 4)
      nxv += dot4(ld4(Ar + k0), ld4(sdxv + k0));
    const float* Br = Bg + i * NU;
#pragma unroll
    for (int m0 = 0; m0 < NU; m0 += 4)
      nxv += dot4(ld4(Br + m0), ld4(sduv + m0));
    sdxv[i] = nxv;
  }
}

extern "C" void kernel_launch(void* const* d_in, const int* in_sizes, int n_in,
                              void* d_out, int out_size, void* d_ws, size_t ws_size,
                              hipStream_t stream) {
  const float* x0  = (const float*)d_in[0];
  const float* x   = (const float*)d_in[1];
  const float* u   = (const float*)d_in[2];
  const float* lmd = (const float*)d_in[3];
  const float* A   = (const float*)d_in[4];
  const float* Bm  = (const float*)d_in[5];
  const float* Qx  = (const float*)d_in[6];
  const float* Ru  = (const float*)d_in[7];
  const float* Qf  = (const float*)d_in[8];
  float* ws  = (float*)d_ws;
  float* out = (float*)d_out;

  hipLaunchKernelGGL(k_riccati_mats, dim3(1), dim3(1024), 0, stream,
                     A, Bm, Qx, Ru, Qf, ws);
  hipLaunchKernelGGL(k_solve, dim3(NB), dim3(256), 0, stream,
                     x0, x, u, lmd, A, Bm, Qx, Ru, Qf, ws, out);
}

// Round 4
// 819.645 us; speedup vs baseline: 1.2108x; 1.2108x over previous
//
#include <hip/hip_runtime.h>

#define DEV __device__ __forceinline__

constexpr int NX = 64, NU = 32, NH = 32, NB = 192;

// workspace float offsets
constexpr int WS_P   = 0;                           // [NH+1][4096]; slot 0 unused -> flags live there
constexpr int WS_QI  = WS_P  + (NH + 1) * NX * NX;  // [NH][1024]  Quu^{-1} row-major
constexpr int WS_QXU = WS_QI + NH * NU * NU;        // [NH][2048]  Qxu x-major
constexpr int WS_K   = WS_QXU + NH * NX * NU;       // [NH][2048]  K u-major

// producer LDS float offsets
constexpr int oA  = 0;      // A  [64][64]
constexpr int oAT = 4096;   // AT [64][64]
constexpr int oB  = 8192;   // B  [64][32]
constexpr int oBT = 10240;  // BT [32][64]
constexpr int oP  = 12288;  // P  [64][64]
constexpr int oG  = 16384;  // G = P*A [64][64]
constexpr int oV  = 20480;  // V = P*B [64][32]
constexpr int oX  = 22528;  // Qxu [64][32]
constexpr int oXT = 24576;  // QxuT [32][65]
constexpr int oQ  = 26656;  // Quu/QuuInv [32][36]
constexpr int oK  = 27808;  // K [32][64]
constexpr int LDSF = 29856; // 119,424 B

DEV float4 ld4(const float* p) { return *reinterpret_cast<const float4*>(p); }
DEV void   st4(float* p, float4 v) { *reinterpret_cast<float4*>(p) = v; }
DEV float  dot4(float4 a, float4 b) {
  return fmaf(a.x, b.x, fmaf(a.y, b.y, fmaf(a.z, b.z, a.w * b.w)));
}
DEV void fma4(float4& a, float s, float4 b) {
  a.x = fmaf(s, b.x, a.x); a.y = fmaf(s, b.y, a.y);
  a.z = fmaf(s, b.z, a.z); a.w = fmaf(s, b.w, a.w);
}
DEV void fma8(float* acc, float s, float4 b0, float4 b1) {
  acc[0] = fmaf(s, b0.x, acc[0]); acc[1] = fmaf(s, b0.y, acc[1]);
  acc[2] = fmaf(s, b0.z, acc[2]); acc[3] = fmaf(s, b0.w, acc[3]);
  acc[4] = fmaf(s, b1.x, acc[4]); acc[5] = fmaf(s, b1.y, acc[5]);
  acc[6] = fmaf(s, b1.z, acc[6]); acc[7] = fmaf(s, b1.w, acc[7]);
}

// ---------------------------------------------------------------------------
// Producer: batch-independent Riccati matrix recursion (block 0, 1024 thr).
// All hot operands LDS-resident; per stage publishes flag[s] after gP/gQI/
// gQxu/gK stores are device-visible.
// ---------------------------------------------------------------------------
DEV void producer(float* lds, const float* Ag, const float* Bg,
                  const float* Qxg, const float* Rug, const float* Qfg,
                  float* ws) {
  const int t = threadIdx.x, lane = t & 63, wv = t >> 6;
  float* sA  = lds + oA;  float* sAT = lds + oAT;
  float* sB  = lds + oB;  float* sBT = lds + oBT;
  float* sP  = lds + oP;  float* sG  = lds + oG;
  float* sV  = lds + oV;  float* sX  = lds + oX;
  float* sXT = lds + oXT; float* sQ  = lds + oQ;
  float* sK  = lds + oK;

  float* gP   = ws + WS_P;
  float* gQI  = ws + WS_QI;
  float* gQxu = ws + WS_QXU;
  float* gK   = ws + WS_K;
  int* flags  = (int*)(ws + WS_P);   // gP slot 0 is never used

  // ---- preload A/AT/B/BT, P=Qf
  {
    const int k = t >> 4, i4 = (t & 15) * 4;
    const float4 a4 = ld4(Ag + k * NX + i4);
    st4(sA + k * NX + i4, a4);
    sAT[(i4 + 0) * NX + k] = a4.x; sAT[(i4 + 1) * NX + k] = a4.y;
    sAT[(i4 + 2) * NX + k] = a4.z; sAT[(i4 + 3) * NX + k] = a4.w;
    st4(sP + k * NX + i4, ld4(Qfg + k * NX + i4));
  }
  if (t < 512) {
    const int k = t >> 3, j4 = (t & 7) * 4;
    const float4 b4 = ld4(Bg + k * NU + j4);
    st4(sB + k * NU + j4, b4);
    sBT[(j4 + 0) * NX + k] = b4.x; sBT[(j4 + 1) * NX + k] = b4.y;
    sBT[(j4 + 2) * NX + k] = b4.z; sBT[(j4 + 3) * NX + k] = b4.w;
  }
  __syncthreads();

  for (int s = NH - 1; s >= 0; --s) {
    // ---- Ph1: gP[s+1] store ; G = P*A ; V = P*B
    {
      const int i0 = wv * 4, j = lane, jb = lane & 31;
      float* gPs = gP + (s + 1) * NX * NX;
#pragma unroll
      for (int r = 0; r < 4; ++r) gPs[(i0 + r) * NX + j] = sP[(i0 + r) * NX + j];

      float g0 = 0, g1 = 0, g2 = 0, g3 = 0, v0 = 0, v1 = 0, v2 = 0, v3 = 0;
#pragma unroll 2
      for (int k0 = 0; k0 < NX; k0 += 4) {
        const float4 p0 = ld4(sP + (i0 + 0) * NX + k0);   // broadcasts
        const float4 p1 = ld4(sP + (i0 + 1) * NX + k0);
        const float4 p2 = ld4(sP + (i0 + 2) * NX + k0);
        const float4 p3 = ld4(sP + (i0 + 3) * NX + k0);
        const float a0 = sA[(k0 + 0) * NX + j], a1 = sA[(k0 + 1) * NX + j];
        const float a2 = sA[(k0 + 2) * NX + j], a3 = sA[(k0 + 3) * NX + j];
        const float b0 = sB[(k0 + 0) * NU + jb], b1 = sB[(k0 + 1) * NU + jb];
        const float b2 = sB[(k0 + 2) * NU + jb], b3 = sB[(k0 + 3) * NU + jb];
        g0 = fmaf(p0.x, a0, g0); g0 = fmaf(p0.y, a1, g0); g0 = fmaf(p0.z, a2, g0); g0 = fmaf(p0.w, a3, g0);
        g1 = fmaf(p1.x, a0, g1); g1 = fmaf(p1.y, a1, g1); g1 = fmaf(p1.z, a2, g1); g1 = fmaf(p1.w, a3, g1);
        g2 = fmaf(p2.x, a0, g2); g2 = fmaf(p2.y, a1, g2); g2 = fmaf(p2.z, a2, g2); g2 = fmaf(p2.w, a3, g2);
        g3 = fmaf(p3.x, a0, g3); g3 = fmaf(p3.y, a1, g3); g3 = fmaf(p3.z, a2, g3); g3 = fmaf(p3.w, a3, g3);
        v0 = fmaf(p0.x, b0, v0); v0 = fmaf(p0.y, b1, v0); v0 = fmaf(p0.z, b2, v0); v0 = fmaf(p0.w, b3, v0);
        v1 = fmaf(p1.x, b0, v1); v1 = fmaf(p1.y, b1, v1); v1 = fmaf(p1.z, b2, v1); v1 = fmaf(p1.w, b3, v1);
        v2 = fmaf(p2.x, b0, v2); v2 = fmaf(p2.y, b1, v2); v2 = fmaf(p2.z, b2, v2); v2 = fmaf(p2.w, b3, v2);
        v3 = fmaf(p3.x, b0, v3); v3 = fmaf(p3.y, b1, v3); v3 = fmaf(p3.z, b2, v3); v3 = fmaf(p3.w, b3, v3);
      }
      sG[(i0 + 0) * NX + j] = g0; sG[(i0 + 1) * NX + j] = g1;
      sG[(i0 + 2) * NX + j] = g2; sG[(i0 + 3) * NX + j] = g3;
      if (j < 32) {
        sV[(i0 + 0) * NU + jb] = v0; sV[(i0 + 1) * NU + jb] = v1;
        sV[(i0 + 2) * NU + jb] = v2; sV[(i0 + 3) * NU + jb] = v3;
      }
    }
    __syncthreads();

    // ---- Ph2: Qxx -> sP (waves 0-7) ; Quu -> sQ (8-11) ; Qxu -> sX/sXT (12-15)
    if (wv < 8) {
      const int a0 = wv * 8, bcol = lane;
      float acc[8];
#pragma unroll
      for (int r = 0; r < 8; ++r) acc[r] = Qxg[(a0 + r) * NX + bcol];
#pragma unroll 2
      for (int k0 = 0; k0 < NX; k0 += 4) {
        const float gk0 = sG[(k0 + 0) * NX + bcol], gk1 = sG[(k0 + 1) * NX + bcol];
        const float gk2 = sG[(k0 + 2) * NX + bcol], gk3 = sG[(k0 + 3) * NX + bcol];
#pragma unroll
        for (int r = 0; r < 8; ++r) {
          const float4 at = ld4(sAT + (a0 + r) * NX + k0);
          acc[r] = fmaf(at.x, gk0, fmaf(at.y, gk1, fmaf(at.z, gk2, fmaf(at.w, gk3, acc[r]))));
        }
      }
#pragma unroll
      for (int r = 0; r < 8; ++r) sP[(a0 + r) * NX + bcol] = acc[r];
    } else if (wv < 12) {
      const int m0 = (wv - 8) * 8;
      const int n = lane & 31, h = lane >> 5, kb = h * 32;
      float acc[8] = {0, 0, 0, 0, 0, 0, 0, 0};
#pragma unroll 2
      for (int kk0 = 0; kk0 < 32; kk0 += 4) {
        const float v0 = sV[(kb + kk0 + 0) * NU + n], v1 = sV[(kb + kk0 + 1) * NU + n];
        const float v2 = sV[(kb + kk0 + 2) * NU + n], v3 = sV[(kb + kk0 + 3) * NU + n];
#pragma unroll
        for (int r = 0; r < 8; ++r) {
          const float4 bt = ld4(sBT + (m0 + r) * NX + kb + kk0);
          acc[r] = fmaf(bt.x, v0, fmaf(bt.y, v1, fmaf(bt.z, v2, fmaf(bt.w, v3, acc[r]))));
        }
      }
#pragma unroll
      for (int r = 0; r < 8; ++r) {
        const float tot = acc[r] + __shfl_xor(acc[r], 32);
        if (h == 0) sQ[(m0 + r) * 36 + n] = Rug[(m0 + r) * NU + n] + tot;
      }
    } else {
      const int a0 = (wv - 12) * 16;
      const int m = lane & 31, h = lane >> 5, kb = h * 32;
      float acc[16];
#pragma unroll
      for (int r = 0; r < 16; ++r) acc[r] = 0.0f;
#pragma unroll 2
      for (int kk0 = 0; kk0 < 32; kk0 += 4) {
        const float v0 = sV[(kb + kk0 + 0) * NU + m], v1 = sV[(kb + kk0 + 1) * NU + m];
        const float v2 = sV[(kb + kk0 + 2) * NU + m], v3 = sV[(kb + kk0 + 3) * NU + m];
#pragma unroll
        for (int r = 0; r < 16; ++r) {
          const float4 at = ld4(sAT + (a0 + r) * NX + kb + kk0);
          acc[r] = fmaf(at.x, v0, fmaf(at.y, v1, fmaf(at.z, v2, fmaf(at.w, v3, acc[r]))));
        }
      }
#pragma unroll
      for (int r = 0; r < 16; ++r) {
        const float tot = acc[r] + __shfl_xor(acc[r], 32);
        if (h == 0) sX[(a0 + r) * NU + m] = tot;
        else        sXT[m * 65 + (a0 + r)] = tot;
      }
    }
    __syncthreads();

    // ---- Ph3: wave 0 register GJ inverse ; waves 1-8 gQxu store
    if (t < 64) {
      const int i = t & 31, h = t >> 5;
      float W[16];
#pragma unroll
      for (int r = 0; r < 16; ++r) W[r] = sQ[i * 36 + h * 16 + r];
#pragma unroll
      for (int j = 0; j < NU; ++j) {
        const int jh = j >> 4, jr = j & 15;
        const float d = __shfl(W[jr], j | (jh << 5));
        const float pinv = 1.0f / d;
        const float f = __shfl(W[jr], i | (jh << 5));
        float pr[16];
#pragma unroll
        for (int r = 0; r < 16; ++r) pr[r] = __shfl(W[r], j | (h << 5));
        float nw[16];
        if (i == j) {
#pragma unroll
          for (int r = 0; r < 16; ++r) nw[r] = pr[r] * pinv;
          if (h == jh) nw[jr] = pinv;
        } else {
          const float g = f * pinv;
#pragma unroll
          for (int r = 0; r < 16; ++r) nw[r] = fmaf(-g, pr[r], W[r]);
          if (h == jh) nw[jr] = -g;
        }
#pragma unroll
        for (int r = 0; r < 16; ++r) W[r] = nw[r];
      }
#pragma unroll
      for (int r = 0; r < 16; ++r) {
        sQ[i * 36 + h * 16 + r] = W[r];
        gQI[s * NU * NU + i * NU + h * 16 + r] = W[r];
      }
    } else if (t - 64 < 512) {
      const int idx = t - 64;
      const int i = idx >> 3, m0 = (idx & 7) * 4;
      st4(gQxu + s * NX * NU + i * NU + m0, ld4(sX + i * NU + m0));
    }
    __syncthreads();

    // ---- Ph4: K(m,j) = -sum_n QI(m,n) * QxuT(n,j) ; gK store
    {
      const int m0 = wv * 2, j = lane;
      float acc0 = 0, acc1 = 0;
#pragma unroll
      for (int n0 = 0; n0 < NU; n0 += 4) {
        const float x0 = sXT[(n0 + 0) * 65 + j], x1 = sXT[(n0 + 1) * 65 + j];
        const float x2 = sXT[(n0 + 2) * 65 + j], x3 = sXT[(n0 + 3) * 65 + j];
        const float4 q0 = ld4(sQ + (m0 + 0) * 36 + n0);
        const float4 q1 = ld4(sQ + (m0 + 1) * 36 + n0);
        acc0 = fmaf(q0.x, x0, fmaf(q0.y, x1, fmaf(q0.z, x2, fmaf(q0.w, x3, acc0))));
        acc1 = fmaf(q1.x, x0, fmaf(q1.y, x1, fmaf(q1.z, x2, fmaf(q1.w, x3, acc1))));
      }
      sK[(m0 + 0) * NX + j] = -acc0;
      sK[(m0 + 1) * NX + j] = -acc1;
      gK[s * NU * NX + (m0 + 0) * NX + j] = -acc0;
      gK[s * NU * NX + (m0 + 1) * NX + j] = -acc1;
    }
    __syncthreads();

    // publish stage s (gP[s+1], gQI[s], gQxu[s], gK[s] all drained by barriers)
    if (t == 0) {
      __threadfence();
      __hip_atomic_store(flags + s, 1, __ATOMIC_RELEASE, __HIP_MEMORY_SCOPE_AGENT);
    }

    // ---- Ph5: P' = Qxx + Qxu * K
    {
      const int i0 = wv * 4, j = lane;
      float acc[4];
#pragma unroll
      for (int r = 0; r < 4; ++r) acc[r] = sP[(i0 + r) * NX + j];
#pragma unroll 2
      for (int m0 = 0; m0 < NU; m0 += 4) {
        const float k0v = sK[(m0 + 0) * NX + j], k1v = sK[(m0 + 1) * NX + j];
        const float k2v = sK[(m0 + 2) * NX + j], k3v = sK[(m0 + 3) * NX + j];
#pragma unroll
        for (int r = 0; r < 4; ++r) {
          const float4 xb = ld4(sX + (i0 + r) * NU + m0);
          acc[r] = fmaf(xb.x, k0v, fmaf(xb.y, k1v, fmaf(xb.z, k2v, fmaf(xb.w, k3v, acc[r]))));
        }
      }
#pragma unroll
      for (int r = 0; r < 4; ++r) sP[(i0 + r) * NX + j] = acc[r];
    }
    __syncthreads();
  }
}

// ---------------------------------------------------------------------------
// Consumer: per-batch residuals + wave-0 recursions, polling stage flags.
// ---------------------------------------------------------------------------
DEV void consumer(float* lds, int b, const float* x0g, const float* xg,
                  const float* ug, const float* lg, const float* Ag,
                  const float* Bg, const float* Qxg, const float* Rug,
                  const float* Qfg, float* ws, float* outp) {
  const int t = threadIdx.x;
  const float* gP   = ws + WS_P;
  const float* gQI  = ws + WS_QI;
  const float* gQxu = ws + WS_QXU;
  const float* gK   = ws + WS_K;
  const int* flags  = (const int*)(ws + WS_P);

  float* sx   = lds;            // 2112 (dead after residuals)
  float* sl   = lds + 2112;     // 2112 (dead after residuals)
  float* su   = lds + 4224;     // 1024 (dead after residuals)
  float* sAT  = lds;            // overlay, stride 68
  float* xres = lds + 5248;     // 2048
  float* lxs  = lds + 7296;     // 2048
  float* lus  = lds + 9344;     // 1024
  float* kv   = lds + 10368;    // 1024
  float* swv  = lds + 11392;    // 64
  float* sqv  = lds + 11456;    // 32
  float* sduv = lds + 11488;    // 32
  float* sdxv = lds + 11520;    // 64

  for (int idx = t; idx < (NH + 1) * NX; idx += 1024) {
    const int s = idx >> 6, i = idx & 63;
    sx[idx] = xg[(s * NB + b) * NX + i];
    sl[idx] = lg[(s * NB + b) * NX + i];
  }
  for (int idx = t; idx < NH * NU; idx += 1024) {
    const int s = idx >> 5, j = idx & 31;
    su[idx] = ug[(s * NB + b) * NU + j];
  }
  __syncthreads();

  if (t < 256) {
    const int s = t >> 3, i0 = (t & 7) * 8;
    float accx[8], accl[8];
#pragma unroll
    for (int ii = 0; ii < 8; ++ii) {
      accx[ii] = -sx[(s + 1) * NX + i0 + ii];
      accl[ii] = -sl[s * NX + i0 + ii];
    }
#pragma unroll 2
    for (int k0 = 0; k0 < NX; k0 += 4) {
      const float4 xv = ld4(sx + s * NX + k0);
#pragma unroll
      for (int ii = 0; ii < 8; ++ii) {
        accx[ii] += dot4(ld4(Ag + (i0 + ii) * NX + k0), xv);
        accl[ii] += dot4(ld4(Qxg + (i0 + ii) * NX + k0), xv);
      }
    }
#pragma unroll 2
    for (int k0 = 0; k0 < NU; k0 += 4) {
      const float4 uv = ld4(su + s * NU + k0);
#pragma unroll
      for (int ii = 0; ii < 8; ++ii)
        accx[ii] += dot4(ld4(Bg + (i0 + ii) * NU + k0), uv);
    }
#pragma unroll 4
    for (int k = 0; k < NX; ++k) {
      const float lv = sl[(s + 1) * NX + k];
      fma8(accl, lv, ld4(Ag + k * NX + i0), ld4(Ag + k * NX + i0 + 4));
    }
#pragma unroll
    for (int ii = 0; ii < 8; ++ii) {
      xres[s * NX + i0 + ii] = accx[ii];
      lxs[s * NX + i0 + ii] = accl[ii];
    }
  }
  if (t < 256) {
    const int s = t >> 3, j0 = (t & 7) * 4;
    float4 acc = {0, 0, 0, 0};
#pragma unroll 2
    for (int k0 = 0; k0 < NU; k0 += 4) {
      const float4 uv = ld4(su + s * NU + k0);
      acc.x += dot4(ld4(Rug + (j0 + 0) * NU + k0), uv);
      acc.y += dot4(ld4(Rug + (j0 + 1) * NU + k0), uv);
      acc.z += dot4(ld4(Rug + (j0 + 2) * NU + k0), uv);
      acc.w += dot4(ld4(Rug + (j0 + 3) * NU + k0), uv);
    }
#pragma unroll 4
    for (int k = 0; k < NX; ++k) {
      const float lv = sl[(s + 1) * NX + k];
      fma4(acc, lv, ld4(Bg + k * NU + j0));
    }
    lus[s * NU + j0 + 0] = acc.x; lus[s * NU + j0 + 1] = acc.y;
    lus[s * NU + j0 + 2] = acc.z; lus[s * NU + j0 + 3] = acc.w;
  }

  float p_i = 0.0f, dx_i = 0.0f;
  if (t < 64) {
    const int i = t;
    float acc = -sl[NH * NX + i];
#pragma unroll 4
    for (int k0 = 0; k0 < NX; k0 += 4)
      acc += dot4(ld4(Qfg + i * NX + k0), ld4(sx + NH * NX + k0));
    p_i = acc;
    dx_i = x0g[b * NX + i] - sx[i];
  }
  __syncthreads();

  for (int idx = t; idx < NX * NX / 4; idx += 1024) {
    const int k = idx >> 4, i4 = (idx & 15) * 4;
    const float4 a4 = ld4(Ag + k * NX + i4);
    sAT[(i4 + 0) * 68 + k] = a4.x;
    sAT[(i4 + 1) * 68 + k] = a4.y;
    sAT[(i4 + 2) * 68 + k] = a4.z;
    sAT[(i4 + 3) * 68 + k] = a4.w;
  }
  __syncthreads();

  if (t >= 64) return;   // wave 0 continues barrier-free

  const int i = t;
  const int j = t & 31;
  const int hh = t >> 5;

  for (int s = NH - 1; s >= 0; --s) {
    // wait for producer stage s (uniform poll, agent-scope acquire)
    while (__hip_atomic_load(flags + s, __ATOMIC_ACQUIRE, __HIP_MEMORY_SCOPE_AGENT) == 0)
      __builtin_amdgcn_s_sleep(2);

    const float* Pr = gP + (s + 1) * NX * NX + i * NX;
    const float* xr = xres + s * NX;
    float w = p_i;
#pragma unroll
    for (int k0 = 0; k0 < NX; k0 += 16) {
      w += dot4(ld4(Pr + k0),      ld4(xr + k0));
      w += dot4(ld4(Pr + k0 + 4),  ld4(xr + k0 + 4));
      w += dot4(ld4(Pr + k0 + 8),  ld4(xr + k0 + 8));
      w += dot4(ld4(Pr + k0 + 12), ld4(xr + k0 + 12));
    }
    swv[i] = w;

    float qx = lxs[s * NX + i];
#pragma unroll
    for (int k0 = 0; k0 < NX; k0 += 16) {
      qx += dot4(ld4(sAT + i * 68 + k0),      ld4(swv + k0));
      qx += dot4(ld4(sAT + i * 68 + k0 + 4),  ld4(swv + k0 + 4));
      qx += dot4(ld4(sAT + i * 68 + k0 + 8),  ld4(swv + k0 + 8));
      qx += dot4(ld4(sAT + i * 68 + k0 + 12), ld4(swv + k0 + 12));
    }

    float qa = 0.0f;
    const int kb = hh * 32;
#pragma unroll 8
    for (int kk = 0; kk < 32; ++kk)
      qa = fmaf(Bg[(kb + kk) * NU + j], swv[kb + kk], qa);
    qa += __shfl_xor(qa, 32);
    const float qu = qa + lus[s * NU + j];
    if (hh == 0) sqv[j] = qu;

    const float* Qr = gQI + s * NU * NU + j * NU + hh * 16;
    float ka = dot4(ld4(Qr),      ld4(sqv + hh * 16))
             + dot4(ld4(Qr + 4),  ld4(sqv + hh * 16 + 4))
             + dot4(ld4(Qr + 8),  ld4(sqv + hh * 16 + 8))
             + dot4(ld4(Qr + 12), ld4(sqv + hh * 16 + 12));
    ka += __shfl_xor(ka, 32);
    if (hh == 0) kv[s * NU + j] = -ka;

    const float* Xr = gQxu + s * NX * NU + i * NU;
    float pp = qx;
#pragma unroll
    for (int m0 = 0; m0 < NU; m0 += 4)
      pp += dot4(ld4(Xr + m0), ld4(kv + s * NU + m0));
    p_i = pp;
  }

  sdxv[i] = dx_i;
  for (int s = 0; s < NH; ++s) {
    const float* Kr = gK + s * NU * NX + j * NX + hh * 32;
    const float* dxh = sdxv + hh * 32;
    float da = 0.0f;
#pragma unroll
    for (int k0 = 0; k0 < 32; k0 += 16) {
      da += dot4(ld4(Kr + k0),      ld4(dxh + k0));
      da += dot4(ld4(Kr + k0 + 4),  ld4(dxh + k0 + 4));
      da += dot4(ld4(Kr + k0 + 8),  ld4(dxh + k0 + 8));
      da += dot4(ld4(Kr + k0 + 12), ld4(dxh + k0 + 12));
    }
    da += __shfl_xor(da, 32);
    const float du = da + kv[s * NU + j];
    if (hh == 0) {
      const int gi = (s * NB + b) * NU + j;
      outp[gi] = ug[gi] + du;
      sduv[j] = du;
    }

    float nxv = xres[s * NX + i];
    const float* Ar = Ag + i * NX;
#pragma unroll
    for (int k0 = 0; k0 < NX; k0 += 4)
      nxv += dot4(ld4(Ar + k0), ld4(sdxv + k0));
    const float* Br = Bg + i * NU;
#pragma unroll
    for (int m0 = 0; m0 < NU; m0 += 4)
      nxv += dot4(ld4(Br + m0), ld4(sduv + m0));
    sdxv[i] = nxv;
  }
}

__global__ void k_zero(float* ws) {
  if (threadIdx.x < 64) ((int*)(ws + WS_P))[threadIdx.x] = 0;
}

__global__ __launch_bounds__(1024) void k_fused(
    const float* __restrict__ x0g, const float* __restrict__ xg,
    const float* __restrict__ ug, const float* __restrict__ lg,
    const float* __restrict__ Ag, const float* __restrict__ Bg,
    const float* __restrict__ Qxg, const float* __restrict__ Rug,
    const float* __restrict__ Qfg, float* __restrict__ ws,
    float* __restrict__ outp) {
  __shared__ __align__(16) float lds[LDSF];
  if (blockIdx.x == 0)
    producer(lds, Ag, Bg, Qxg, Rug, Qfg, ws);
  else
    consumer(lds, blockIdx.x - 1, x0g, xg, ug, lg, Ag, Bg, Qxg, Rug, Qfg, ws, outp);
}

extern "C" void kernel_launch(void* const* d_in, const int* in_sizes, int n_in,
                              void* d_out, int out_size, void* d_ws, size_t ws_size,
                              hipStream_t stream) {
  const float* x0  = (const float*)d_in[0];
  const float* x   = (const float*)d_in[1];
  const float* u   = (const float*)d_in[2];
  const float* lmd = (const float*)d_in[3];
  const float* A   = (const float*)d_in[4];
  const float* Bm  = (const float*)d_in[5];
  const float* Qx  = (const float*)d_in[6];
  const float* Ru  = (const float*)d_in[7];
  const float* Qf  = (const float*)d_in[8];
  float* ws  = (float*)d_ws;
  float* out = (float*)d_out;

  hipLaunchKernelGGL(k_zero, dim3(1), dim3(64), 0, stream, ws);
  hipLaunchKernelGGL(k_fused, dim3(NB + 1), dim3(1024), 0, stream,
                     x0, x, u, lmd, A, Bm, Qx, Ru, Qf, ws, out);
}

// Round 5
// 572.089 us; speedup vs baseline: 1.7348x; 1.4327x over previous
//
#include <hip/hip_runtime.h>

#define DEV __device__ __forceinline__

constexpr int NX = 64, NU = 32, NH = 32, NB = 192;

// workspace float offsets
constexpr int WS_P  = 0;                           // [NH+1][4096]; slot 0 -> flags
constexpr int WS_QI = WS_P  + (NH + 1) * NX * NX;  // [NH][1024]  Quu^{-1} row-major
constexpr int WS_XT = WS_QI + NH * NU * NU;        // [NH][32*64] Qxu^T (u-major)
constexpr int WS_K  = WS_XT + NH * NU * NX;        // [NH][32*64] K row-major (u,x)

// producer LDS float offsets (padded strides: 68 for 64-col, 36 for 32-col)
constexpr int oA   = 0;      // A   [64][64]  (read-only rows)
constexpr int oB   = 4096;   // B   [64][36]
constexpr int oQx  = 6400;   // Qx  [64][68]
constexpr int oRu  = 10752;  // Ru  [32][32]
constexpr int oP   = 11776;  // P/Qxx/P' [64][68]
constexpr int oG   = 16128;  // G = P*A  [64][68]
constexpr int oV   = 20480;  // V = P*B  [64][36]
constexpr int oXT  = 22784;  // Qxu^T    [32][68]
constexpr int oQ   = 24960;  // Quu/QI   [32][36]
constexpr int oK   = 26112;  // K        [32][68]
constexpr int LDSF = 28288;  // 113,152 B

DEV float4 ld4(const float* p) { return *reinterpret_cast<const float4*>(p); }
DEV void   st4(float* p, float4 v) { *reinterpret_cast<float4*>(p) = v; }
DEV float  dot4(float4 a, float4 b) {
  return fmaf(a.x, b.x, fmaf(a.y, b.y, fmaf(a.z, b.z, a.w * b.w)));
}
DEV void fma4(float4& a, float s, float4 b) {
  a.x = fmaf(s, b.x, a.x); a.y = fmaf(s, b.y, a.y);
  a.z = fmaf(s, b.z, a.z); a.w = fmaf(s, b.w, a.w);
}
DEV void fma8(float* acc, float s, float4 b0, float4 b1) {
  acc[0] = fmaf(s, b0.x, acc[0]); acc[1] = fmaf(s, b0.y, acc[1]);
  acc[2] = fmaf(s, b0.z, acc[2]); acc[3] = fmaf(s, b0.w, acc[3]);
  acc[4] = fmaf(s, b1.x, acc[4]); acc[5] = fmaf(s, b1.y, acc[5]);
  acc[6] = fmaf(s, b1.z, acc[6]); acc[7] = fmaf(s, b1.w, acc[7]);
}
DEV void mma48(float (&acc)[4][8], float4 m4, float4 nA, float4 nB) {
  const float mr[4] = {m4.x, m4.y, m4.z, m4.w};
  const float nc[8] = {nA.x, nA.y, nA.z, nA.w, nB.x, nB.y, nB.z, nB.w};
#pragma unroll
  for (int r = 0; r < 4; ++r)
#pragma unroll
    for (int c = 0; c < 8; ++c)
      acc[r][c] = fmaf(mr[r], nc[c], acc[r][c]);
}
DEV void mma44(float (&acc)[4][4], float4 m4, float4 nv) {
  const float mr[4] = {m4.x, m4.y, m4.z, m4.w};
#pragma unroll
  for (int r = 0; r < 4; ++r) {
    acc[r][0] = fmaf(mr[r], nv.x, acc[r][0]);
    acc[r][1] = fmaf(mr[r], nv.y, acc[r][1]);
    acc[r][2] = fmaf(mr[r], nv.z, acc[r][2]);
    acc[r][3] = fmaf(mr[r], nv.w, acc[r][3]);
  }
}
DEV float4 pk4(const float* a) { float4 v; v.x = a[0]; v.y = a[1]; v.z = a[2]; v.w = a[3]; return v; }

// ---------------------------------------------------------------------------
// Producer: block 0, 1024 threads. All GEMMs are M^T N with row-chunk b128
// reads (P, QI symmetric). 4 barriers/stage; GJ overlapped with Qxx/XT.
// ---------------------------------------------------------------------------
DEV void producer(float* lds, const float* Ag, const float* Bg,
                  const float* Qxg, const float* Rug, const float* Qfg,
                  float* ws) {
  const int t = threadIdx.x, lane = t & 63, wv = t >> 6;
  float* sA  = lds + oA;   float* sB  = lds + oB;
  float* sQx = lds + oQx;  float* sRu = lds + oRu;
  float* sP  = lds + oP;   float* sG  = lds + oG;
  float* sV  = lds + oV;   float* sXT = lds + oXT;
  float* sQ  = lds + oQ;   float* sK  = lds + oK;

  float* gP  = ws + WS_P;
  float* gQI = ws + WS_QI;
  float* gXT = ws + WS_XT;
  float* gK  = ws + WS_K;
  int* flags = (int*)(ws + WS_P);   // gP slot 0 unused

  // ---- preload (stage-invariant)
  {
    st4(sA + t * 4, ld4(Ag + t * 4));
    const int row = t >> 4, c0 = (t & 15) * 4;
    st4(sQx + row * 68 + c0, ld4(Qxg + row * NX + c0));
    st4(sP  + row * 68 + c0, ld4(Qfg + row * NX + c0));
    if (t < 512) {
      const int rb = t >> 3, cb = (t & 7) * 4;
      st4(sB + rb * 36 + cb, ld4(Bg + rb * NU + cb));
    }
    if (t < 256) st4(sRu + t * 4, ld4(Rug + t * 4));
  }
  __syncthreads();

  for (int s = NH - 1; s >= 0; --s) {
    // ================ Ph1: V = P*B (w0) ; G = P*A (w1-2) ; gP store (w3-6)
    if (wv == 0) {
      const int i0 = (lane & 15) * 4, n0 = (lane >> 4) * 8;
      float acc[4][8] = {};
#pragma unroll 4
      for (int k = 0; k < NX; ++k)
        mma48(acc, ld4(sP + k * 68 + i0), ld4(sB + k * 36 + n0), ld4(sB + k * 36 + n0 + 4));
#pragma unroll
      for (int r = 0; r < 4; ++r) {
        st4(sV + (i0 + r) * 36 + n0, pk4(acc[r]));
        st4(sV + (i0 + r) * 36 + n0 + 4, pk4(acc[r] + 4));
      }
    } else if (wv <= 2) {
      const int i0 = (wv - 1) * 32 + (lane & 7) * 4, j0 = (lane >> 3) * 8;
      float acc[4][8] = {};
#pragma unroll 4
      for (int k = 0; k < NX; ++k)
        mma48(acc, ld4(sP + k * 68 + i0), ld4(sA + k * NX + j0), ld4(sA + k * NX + j0 + 4));
#pragma unroll
      for (int r = 0; r < 4; ++r) {
        st4(sG + (i0 + r) * 68 + j0, pk4(acc[r]));
        st4(sG + (i0 + r) * 68 + j0 + 4, pk4(acc[r] + 4));
      }
    } else if (wv <= 6) {
      const int idx = (wv - 3) * 64 + lane;           // 0..255, 16 floats each
      const int ri = idx >> 2, c0 = (idx & 3) * 16;
      float* gPs = gP + (s + 1) * NX * NX;
#pragma unroll
      for (int q = 0; q < 4; ++q)
        st4(gPs + ri * NX + c0 + q * 4, ld4(sP + ri * 68 + c0 + q * 4));
    }
    __syncthreads();

    // ================ Ph2: w0: Quu + GJ inverse + gQI ; w1-2: Qxx ; w3: XT
    if (wv == 0) {
      // Quu = Ru + B^T V  (4x4 tiles)
      const int m0 = (lane & 7) * 4, n0 = (lane >> 3) * 4;
      float acc[4][4];
#pragma unroll
      for (int r = 0; r < 4; ++r) {
        const float4 rv = ld4(sRu + (m0 + r) * NU + n0);
        acc[r][0] = rv.x; acc[r][1] = rv.y; acc[r][2] = rv.z; acc[r][3] = rv.w;
      }
#pragma unroll 4
      for (int k = 0; k < NX; ++k)
        mma44(acc, ld4(sB + k * 36 + m0), ld4(sV + k * 36 + n0));
#pragma unroll
      for (int r = 0; r < 4; ++r) st4(sQ + (m0 + r) * 36 + n0, pk4(acc[r]));

      // register GJ inverse (wave-sync LDS read-back)
      const int i = lane & 31, h = lane >> 5;
      float W[16];
#pragma unroll
      for (int r = 0; r < 16; ++r) W[r] = sQ[i * 36 + h * 16 + r];
#pragma unroll
      for (int j = 0; j < NU; ++j) {
        const int jh = j >> 4, jr = j & 15;
        const float d = __shfl(W[jr], j | (jh << 5));
        const float pinv = 1.0f / d;
        const float f = __shfl(W[jr], i | (jh << 5));
        float pr[16];
#pragma unroll
        for (int r = 0; r < 16; ++r) pr[r] = __shfl(W[r], j | (h << 5));
        float nw[16];
        if (i == j) {
#pragma unroll
          for (int r = 0; r < 16; ++r) nw[r] = pr[r] * pinv;
          if (h == jh) nw[jr] = pinv;
        } else {
          const float g = f * pinv;
#pragma unroll
          for (int r = 0; r < 16; ++r) nw[r] = fmaf(-g, pr[r], W[r]);
          if (h == jh) nw[jr] = -g;
        }
#pragma unroll
        for (int r = 0; r < 16; ++r) W[r] = nw[r];
      }
#pragma unroll
      for (int q = 0; q < 4; ++q) {
        st4(sQ + i * 36 + h * 16 + q * 4, pk4(W + q * 4));
        st4(gQI + s * NU * NU + i * NU + h * 16 + q * 4, pk4(W + q * 4));
      }
    } else if (wv <= 2) {
      // Qxx = Qx + A^T G  -> sP
      const int i0 = (wv - 1) * 32 + (lane & 7) * 4, j0 = (lane >> 3) * 8;
      float acc[4][8];
#pragma unroll
      for (int r = 0; r < 4; ++r) {
        const float4 q0 = ld4(sQx + (i0 + r) * 68 + j0);
        const float4 q1 = ld4(sQx + (i0 + r) * 68 + j0 + 4);
        acc[r][0] = q0.x; acc[r][1] = q0.y; acc[r][2] = q0.z; acc[r][3] = q0.w;
        acc[r][4] = q1.x; acc[r][5] = q1.y; acc[r][6] = q1.z; acc[r][7] = q1.w;
      }
#pragma unroll 4
      for (int k = 0; k < NX; ++k)
        mma48(acc, ld4(sA + k * NX + i0), ld4(sG + k * 68 + j0), ld4(sG + k * 68 + j0 + 4));
#pragma unroll
      for (int r = 0; r < 4; ++r) {
        st4(sP + (i0 + r) * 68 + j0, pk4(acc[r]));
        st4(sP + (i0 + r) * 68 + j0 + 4, pk4(acc[r] + 4));
      }
    } else if (wv == 3) {
      // XT[n][i] = sum_k V[k][n] A[k][i]  -> sXT + gXT
      const int n0 = (lane & 7) * 4, i0 = (lane >> 3) * 8;
      float acc[4][8] = {};
#pragma unroll 4
      for (int k = 0; k < NX; ++k)
        mma48(acc, ld4(sV + k * 36 + n0), ld4(sA + k * NX + i0), ld4(sA + k * NX + i0 + 4));
      float* gXs = gXT + s * NU * NX;
#pragma unroll
      for (int r = 0; r < 4; ++r) {
        st4(sXT + (n0 + r) * 68 + i0, pk4(acc[r]));
        st4(sXT + (n0 + r) * 68 + i0 + 4, pk4(acc[r] + 4));
        st4(gXs + (n0 + r) * NX + i0, pk4(acc[r]));
        st4(gXs + (n0 + r) * NX + i0 + 4, pk4(acc[r] + 4));
      }
    }
    __syncthreads();

    // ================ Ph3: K = -QI * XT  (w0) ; gK store
    if (wv == 0) {
      const int m0 = (lane & 7) * 4, j0 = (lane >> 3) * 8;
      float acc[4][8] = {};
#pragma unroll 4
      for (int n = 0; n < NU; ++n)
        mma48(acc, ld4(sQ + n * 36 + m0), ld4(sXT + n * 68 + j0), ld4(sXT + n * 68 + j0 + 4));
      float* gKs = gK + s * NU * NX;
#pragma unroll
      for (int r = 0; r < 4; ++r) {
#pragma unroll
        for (int c = 0; c < 8; ++c) acc[r][c] = -acc[r][c];
        st4(sK + (m0 + r) * 68 + j0, pk4(acc[r]));
        st4(sK + (m0 + r) * 68 + j0 + 4, pk4(acc[r] + 4));
        st4(gKs + (m0 + r) * NX + j0, pk4(acc[r]));
        st4(gKs + (m0 + r) * NX + j0 + 4, pk4(acc[r] + 4));
      }
    }
    __syncthreads();

    // publish stage s (all stage-s consumer data drained by the barrier above)
    if (t == 1023) {
      __threadfence();
      __hip_atomic_store(flags + s, 1, __ATOMIC_RELEASE, __HIP_MEMORY_SCOPE_AGENT);
    }

    // ================ Ph4: P' = Qxx + sum_m XT[m][i] K[m][j]  (w0-1)
    if (wv <= 1) {
      const int i0 = wv * 32 + (lane & 7) * 4, j0 = (lane >> 3) * 8;
      float acc[4][8];
#pragma unroll
      for (int r = 0; r < 4; ++r) {
        const float4 p0 = ld4(sP + (i0 + r) * 68 + j0);
        const float4 p1 = ld4(sP + (i0 + r) * 68 + j0 + 4);
        acc[r][0] = p0.x; acc[r][1] = p0.y; acc[r][2] = p0.z; acc[r][3] = p0.w;
        acc[r][4] = p1.x; acc[r][5] = p1.y; acc[r][6] = p1.z; acc[r][7] = p1.w;
      }
#pragma unroll 4
      for (int n = 0; n < NU; ++n)
        mma48(acc, ld4(sXT + n * 68 + i0), ld4(sK + n * 68 + j0), ld4(sK + n * 68 + j0 + 4));
#pragma unroll
      for (int r = 0; r < 4; ++r) {
        st4(sP + (i0 + r) * 68 + j0, pk4(acc[r]));
        st4(sP + (i0 + r) * 68 + j0 + 4, pk4(acc[r] + 4));
      }
    }
    __syncthreads();
  }
}

// ---------------------------------------------------------------------------
// Consumer: per-batch residuals + wave-0 recursions, polling stage flags.
// ---------------------------------------------------------------------------
DEV void consumer(float* lds, int b, const float* x0g, const float* xg,
                  const float* ug, const float* lg, const float* Ag,
                  const float* Bg, const float* Qxg, const float* Rug,
                  const float* Qfg, float* ws, float* outp) {
  const int t = threadIdx.x;
  const float* gP  = ws + WS_P;
  const float* gQI = ws + WS_QI;
  const float* gXT = ws + WS_XT;
  const float* gK  = ws + WS_K;
  const int* flags = (const int*)(ws + WS_P);

  float* sx   = lds;            // 2112 (dead after residuals)
  float* sl   = lds + 2112;     // 2112 (dead after residuals)
  float* su   = lds + 4224;     // 1024 (dead after residuals)
  float* sAT  = lds;            // overlay, stride 68
  float* xres = lds + 5248;     // 2048
  float* lxs  = lds + 7296;     // 2048
  float* lus  = lds + 9344;     // 1024
  float* kv   = lds + 10368;    // 1024
  float* swv  = lds + 11392;    // 64
  float* sqv  = lds + 11456;    // 32
  float* sduv = lds + 11488;    // 32
  float* sdxv = lds + 11520;    // 64

  for (int idx = t; idx < (NH + 1) * NX; idx += 1024) {
    const int s = idx >> 6, i = idx & 63;
    sx[idx] = xg[(s * NB + b) * NX + i];
    sl[idx] = lg[(s * NB + b) * NX + i];
  }
  for (int idx = t; idx < NH * NU; idx += 1024) {
    const int s = idx >> 5, j = idx & 31;
    su[idx] = ug[(s * NB + b) * NU + j];
  }
  __syncthreads();

  if (t < 256) {
    const int s = t >> 3, i0 = (t & 7) * 8;
    float accx[8], accl[8];
#pragma unroll
    for (int ii = 0; ii < 8; ++ii) {
      accx[ii] = -sx[(s + 1) * NX + i0 + ii];
      accl[ii] = -sl[s * NX + i0 + ii];
    }
#pragma unroll 2
    for (int k0 = 0; k0 < NX; k0 += 4) {
      const float4 xv = ld4(sx + s * NX + k0);
#pragma unroll
      for (int ii = 0; ii < 8; ++ii) {
        accx[ii] += dot4(ld4(Ag + (i0 + ii) * NX + k0), xv);
        accl[ii] += dot4(ld4(Qxg + (i0 + ii) * NX + k0), xv);
      }
    }
#pragma unroll 2
    for (int k0 = 0; k0 < NU; k0 += 4) {
      const float4 uv = ld4(su + s * NU + k0);
#pragma unroll
      for (int ii = 0; ii < 8; ++ii)
        accx[ii] += dot4(ld4(Bg + (i0 + ii) * NU + k0), uv);
    }
#pragma unroll 4
    for (int k = 0; k < NX; ++k) {
      const float lv = sl[(s + 1) * NX + k];
      fma8(accl, lv, ld4(Ag + k * NX + i0), ld4(Ag + k * NX + i0 + 4));
    }
#pragma unroll
    for (int ii = 0; ii < 8; ++ii) {
      xres[s * NX + i0 + ii] = accx[ii];
      lxs[s * NX + i0 + ii] = accl[ii];
    }
  }
  if (t < 256) {
    const int s = t >> 3, j0 = (t & 7) * 4;
    float4 acc = {0, 0, 0, 0};
#pragma unroll 2
    for (int k0 = 0; k0 < NU; k0 += 4) {
      const float4 uv = ld4(su + s * NU + k0);
      acc.x += dot4(ld4(Rug + (j0 + 0) * NU + k0), uv);
      acc.y += dot4(ld4(Rug + (j0 + 1) * NU + k0), uv);
      acc.z += dot4(ld4(Rug + (j0 + 2) * NU + k0), uv);
      acc.w += dot4(ld4(Rug + (j0 + 3) * NU + k0), uv);
    }
#pragma unroll 4
    for (int k = 0; k < NX; ++k) {
      const float lv = sl[(s + 1) * NX + k];
      fma4(acc, lv, ld4(Bg + k * NU + j0));
    }
    lus[s * NU + j0 + 0] = acc.x; lus[s * NU + j0 + 1] = acc.y;
    lus[s * NU + j0 + 2] = acc.z; lus[s * NU + j0 + 3] = acc.w;
  }

  float p_i = 0.0f, dx_i = 0.0f;
  if (t < 64) {
    const int i = t;
    float acc = -sl[NH * NX + i];
#pragma unroll 4
    for (int k0 = 0; k0 < NX; k0 += 4)
      acc += dot4(ld4(Qfg + i * NX + k0), ld4(sx + NH * NX + k0));
    p_i = acc;
    dx_i = x0g[b * NX + i] - sx[i];
  }
  __syncthreads();

  for (int idx = t; idx < NX * NX / 4; idx += 1024) {
    const int k = idx >> 4, i4 = (idx & 15) * 4;
    const float4 a4 = ld4(Ag + k * NX + i4);
    sAT[(i4 + 0) * 68 + k] = a4.x;
    sAT[(i4 + 1) * 68 + k] = a4.y;
    sAT[(i4 + 2) * 68 + k] = a4.z;
    sAT[(i4 + 3) * 68 + k] = a4.w;
  }
  __syncthreads();

  if (t >= 64) return;   // wave 0 continues barrier-free

  const int i = t;
  const int j = t & 31;
  const int hh = t >> 5;

  for (int s = NH - 1; s >= 0; --s) {
    while (__hip_atomic_load(flags + s, __ATOMIC_ACQUIRE, __HIP_MEMORY_SCOPE_AGENT) == 0)
      __builtin_amdgcn_s_sleep(16);

    const float* Pr = gP + (s + 1) * NX * NX + i * NX;
    const float* xr = xres + s * NX;
    float w = p_i;
#pragma unroll
    for (int k0 = 0; k0 < NX; k0 += 16) {
      w += dot4(ld4(Pr + k0),      ld4(xr + k0));
      w += dot4(ld4(Pr + k0 + 4),  ld4(xr + k0 + 4));
      w += dot4(ld4(Pr + k0 + 8),  ld4(xr + k0 + 8));
      w += dot4(ld4(Pr + k0 + 12), ld4(xr + k0 + 12));
    }
    swv[i] = w;

    float qx = lxs[s * NX + i];
#pragma unroll
    for (int k0 = 0; k0 < NX; k0 += 16) {
      qx += dot4(ld4(sAT + i * 68 + k0),      ld4(swv + k0));
      qx += dot4(ld4(sAT + i * 68 + k0 + 4),  ld4(swv + k0 + 4));
      qx += dot4(ld4(sAT + i * 68 + k0 + 8),  ld4(swv + k0 + 8));
      qx += dot4(ld4(sAT + i * 68 + k0 + 12), ld4(swv + k0 + 12));
    }

    float qa = 0.0f;
    const int kb = hh * 32;
#pragma unroll 8
    for (int kk = 0; kk < 32; ++kk)
      qa = fmaf(Bg[(kb + kk) * NU + j], swv[kb + kk], qa);
    qa += __shfl_xor(qa, 32);
    const float qu = qa + lus[s * NU + j];
    if (hh == 0) sqv[j] = qu;

    const float* Qr = gQI + s * NU * NU + j * NU + hh * 16;
    float ka = dot4(ld4(Qr),      ld4(sqv + hh * 16))
             + dot4(ld4(Qr + 4),  ld4(sqv + hh * 16 + 4))
             + dot4(ld4(Qr + 8),  ld4(sqv + hh * 16 + 8))
             + dot4(ld4(Qr + 12), ld4(sqv + hh * 16 + 12));
    ka += __shfl_xor(ka, 32);
    if (hh == 0) kv[s * NU + j] = -ka;

    // p = qx + sum_m XT[m][i] * k_m   (coalesced gXT reads)
    const float* Xs = gXT + s * NU * NX;
    float pp = qx;
#pragma unroll 8
    for (int m = 0; m < NU; ++m)
      pp = fmaf(Xs[m * NX + i], kv[s * NU + m], pp);
    p_i = pp;
  }

  sdxv[i] = dx_i;
  for (int s = 0; s < NH; ++s) {
    const float* Kr = gK + s * NU * NX + j * NX + hh * 32;
    const float* dxh = sdxv + hh * 32;
    float da = 0.0f;
#pragma unroll
    for (int k0 = 0; k0 < 32; k0 += 16) {
      da += dot4(ld4(Kr + k0),      ld4(dxh + k0));
      da += dot4(ld4(Kr + k0 + 4),  ld4(dxh + k0 + 4));
      da += dot4(ld4(Kr + k0 + 8),  ld4(dxh + k0 + 8));
      da += dot4(ld4(Kr + k0 + 12), ld4(dxh + k0 + 12));
    }
    da += __shfl_xor(da, 32);
    const float du = da + kv[s * NU + j];
    if (hh == 0) {
      const int gi = (s * NB + b) * NU + j;
      outp[gi] = ug[gi] + du;
      sduv[j] = du;
    }

    float nxv = xres[s * NX + i];
    const float* Ar = Ag + i * NX;
#pragma unroll
    for (int k0 = 0; k0 < NX; k0 += 4)
      nxv += dot4(ld4(Ar + k0), ld4(sdxv + k0));
    const float* Br = Bg + i * NU;
#pragma unroll
    for (int m0 = 0; m0 < NU; m0 += 4)
      nxv += dot4(ld4(Br + m0), ld4(sduv + m0));
    sdxv[i] = nxv;
  }
}

__global__ void k_zero(float* ws) {
  if (threadIdx.x < 64) ((int*)(ws + WS_P))[threadIdx.x] = 0;
}

__global__ __launch_bounds__(1024) void k_fused(
    const float* __restrict__ x0g, const float* __restrict__ xg,
    const float* __restrict__ ug, const float* __restrict__ lg,
    const float* __restrict__ Ag, const float* __restrict__ Bg,
    const float* __restrict__ Qxg, const float* __restrict__ Rug,
    const float* __restrict__ Qfg, float* __restrict__ ws,
    float* __restrict__ outp) {
  __shared__ __align__(16) float lds[LDSF];
  if (blockIdx.x == 0)
    producer(lds, Ag, Bg, Qxg, Rug, Qfg, ws);
  else
    consumer(lds, blockIdx.x - 1, x0g, xg, ug, lg, Ag, Bg, Qxg, Rug, Qfg, ws, outp);
}

extern "C" void kernel_launch(void* const* d_in, const int* in_sizes, int n_in,
                              void* d_out, int out_size, void* d_ws, size_t ws_size,
                              hipStream_t stream) {
  const float* x0  = (const float*)d_in[0];
  const float* x   = (const float*)d_in[1];
  const float* u   = (const float*)d_in[2];
  const float* lmd = (const float*)d_in[3];
  const float* A   = (const float*)d_in[4];
  const float* Bm  = (const float*)d_in[5];
  const float* Qx  = (const float*)d_in[6];
  const float* Ru  = (const float*)d_in[7];
  const float* Qf  = (const float*)d_in[8];
  float* ws  = (float*)d_ws;
  float* out = (float*)d_out;

  hipLaunchKernelGGL(k_zero, dim3(1), dim3(64), 0, stream, ws);
  hipLaunchKernelGGL(k_fused, dim3(NB + 1), dim3(1024), 0, stream,
                     x0, x, u, lmd, A, Bm, Qx, Ru, Qf, ws, out);
}

// Round 6
// 449.803 us; speedup vs baseline: 2.2064x; 1.2719x over previous
//
#include <hip/hip_runtime.h>

#define DEV __device__ __forceinline__

constexpr int NX = 64, NU = 32, NH = 32, NB = 192;

// workspace float offsets
constexpr int WS_P  = 0;                           // [NH+1][4096]; slot 0 -> flags
constexpr int WS_QI = WS_P  + (NH + 1) * NX * NX;  // [NH][1024]  Quu^{-1}
constexpr int WS_XT = WS_QI + NH * NU * NU;        // [NH][32*64] Qxu^T (u-major)
constexpr int WS_K  = WS_XT + NH * NU * NX;        // [NH][32*64] K row-major

typedef __attribute__((ext_vector_type(8))) short bf16x8;
typedef __attribute__((ext_vector_type(4))) float f32x4;
typedef __attribute__((ext_vector_type(4))) unsigned short us4;

// producer smem byte offsets (bf16 packs stride 72 el = 144 B, or 40 el = 80 B)
constexpr int oM2Th = 0;        // M2T hi [96][72]
constexpr int oM2Tl = 13824;
constexpr int oPh   = 27648;    // P pack hi [64][72]
constexpr int oPl   = 36864;
constexpr int oTTh  = 46080;    // T^T pack hi [96][72]
constexpr int oTTl  = 59904;
constexpr int oXUh  = 73728;    // Qxu pack hi [64][40]
constexpr int oXUl  = 78848;
constexpr int oKTh  = 83968;    // KT pack hi [64][40]
constexpr int oKTl  = 89088;
constexpr int oQIh  = 94208;    // QI pack hi [32][40]
constexpr int oQIl  = 96768;
constexpr int oQXX  = 99328;    // fp32 [64][68]
constexpr int oQUU  = 116736;   // fp32 [32][36]
constexpr int SMEMB = 121344;

DEV unsigned short bfh(float x) {
  unsigned u = __float_as_uint(x);
  return (unsigned short)((u + 0x7FFFu + ((u >> 16) & 1u)) >> 16);
}
DEV float bf2f(unsigned short h) { return __uint_as_float(((unsigned)h) << 16); }
DEV bf16x8 ldf(const char* base, int byteoff) { return *(const bf16x8*)(base + byteoff); }
DEV void st_pack4(char* hb, char* lb, int elemoff, f32x4 v) {
  us4 h, l;
#pragma unroll
  for (int r = 0; r < 4; ++r) {
    unsigned short hh = bfh(v[r]);
    h[r] = (short)hh;
    l[r] = (short)bfh(v[r] - bf2f(hh));
  }
  *(us4*)(hb + elemoff * 2) = h;
  *(us4*)(lb + elemoff * 2) = l;
}

DEV float4 ld4(const float* p) { return *reinterpret_cast<const float4*>(p); }
DEV void   st4(float* p, float4 v) { *reinterpret_cast<float4*>(p) = v; }
DEV float  dot4(float4 a, float4 b) {
  return fmaf(a.x, b.x, fmaf(a.y, b.y, fmaf(a.z, b.z, a.w * b.w)));
}
DEV void fma4(float4& a, float s, float4 b) {
  a.x = fmaf(s, b.x, a.x); a.y = fmaf(s, b.y, a.y);
  a.z = fmaf(s, b.z, a.z); a.w = fmaf(s, b.w, a.w);
}
DEV void fma8(float* acc, float s, float4 b0, float4 b1) {
  acc[0] = fmaf(s, b0.x, acc[0]); acc[1] = fmaf(s, b0.y, acc[1]);
  acc[2] = fmaf(s, b0.z, acc[2]); acc[3] = fmaf(s, b0.w, acc[3]);
  acc[4] = fmaf(s, b1.x, acc[4]); acc[5] = fmaf(s, b1.y, acc[5]);
  acc[6] = fmaf(s, b1.z, acc[6]); acc[7] = fmaf(s, b1.w, acc[7]);
}

#define MFMA16(a, b, c) __builtin_amdgcn_mfma_f32_16x16x32_bf16(a, b, c, 0, 0, 0)

// ---------------------------------------------------------------------------
// Producer (block 0, 512 threads / 8 waves): split-bf16 MFMA Riccati recursion.
// ---------------------------------------------------------------------------
DEV void producer(char* smem, const float* Ag, const float* Bg,
                  const float* Qxg, const float* Rug, const float* Qfg,
                  float* ws) {
  const int t = threadIdx.x, lane = t & 63, wv = t >> 6;
  const int l15 = lane & 15, l4 = lane >> 4;

  char* M2Th = smem + oM2Th; char* M2Tl = smem + oM2Tl;
  char* Ph   = smem + oPh;   char* Pl   = smem + oPl;
  char* TTh  = smem + oTTh;  char* TTl  = smem + oTTl;
  char* XUh  = smem + oXUh;  char* XUl  = smem + oXUl;
  char* KTh  = smem + oKTh;  char* KTl  = smem + oKTl;
  char* QIh  = smem + oQIh;  char* QIl  = smem + oQIl;
  float* QXX = (float*)(smem + oQXX);
  float* QUU = (float*)(smem + oQUU);

  float* gP  = ws + WS_P;
  float* gQI = ws + WS_QI;
  float* gXT = ws + WS_XT;
  float* gK  = ws + WS_K;
  int* flags = (int*)(ws + WS_P);   // gP slot 0 never written as P

  // ---- static packs: M2T[j][m] = (j<64 ? A[m][j] : B[m][j-64]); P = Qf; gP[32]=Qf
  for (int idx = t; idx < 96 * 64; idx += 512) {
    const int j = idx >> 6, m = idx & 63;
    const float v = (j < 64) ? Ag[m * 64 + j] : Bg[m * 32 + (j - 64)];
    const unsigned short h = bfh(v);
    *(unsigned short*)(M2Th + (j * 72 + m) * 2) = h;
    *(unsigned short*)(M2Tl + (j * 72 + m) * 2) = bfh(v - bf2f(h));
  }
  for (int idx = t; idx < 64 * 64; idx += 512) {
    const int r = idx >> 6, c = idx & 63;
    const float v = Qfg[idx];
    const unsigned short h = bfh(v);
    *(unsigned short*)(Ph + (r * 72 + c) * 2) = h;
    *(unsigned short*)(Pl + (r * 72 + c) * 2) = bfh(v - bf2f(h));
    gP[32 * 4096 + idx] = v;
  }
  __syncthreads();

  for (int s = NH - 1; s >= 0; --s) {
    // ---- PhA: T = P*M2 -> TT pack. 24 tiles (tt = jT*4+mT)
    for (int tt = wv; tt < 24; tt += 8) {
      const int mT = tt & 3, jT = tt >> 2;
      f32x4 acc = {0.f, 0.f, 0.f, 0.f};
#pragma unroll
      for (int kp = 0; kp < 2; ++kp) {
        const int ko = (kp * 32 + l4 * 8) * 2;
        const bf16x8 ah = ldf(Ph,   (mT * 16 + l15) * 144 + ko);
        const bf16x8 al = ldf(Pl,   (mT * 16 + l15) * 144 + ko);
        const bf16x8 bh = ldf(M2Th, (jT * 16 + l15) * 144 + ko);
        const bf16x8 bl = ldf(M2Tl, (jT * 16 + l15) * 144 + ko);
        acc = MFMA16(ah, bh, acc);
        acc = MFMA16(ah, bl, acc);
        acc = MFMA16(al, bh, acc);
      }
      st_pack4(TTh, TTl, (jT * 16 + l15) * 72 + mT * 16 + l4 * 4, acc);
    }
    __syncthreads();

    // ---- PhB: S = T^T * M2 (36 tiles). Blocks routed by region.
    for (int tt = wv; tt < 36; tt += 8) {
      const int jT = tt / 6, iT = tt % 6;
      f32x4 acc = {0.f, 0.f, 0.f, 0.f};
#pragma unroll
      for (int kp = 0; kp < 2; ++kp) {
        const int ko = (kp * 32 + l4 * 8) * 2;
        const bf16x8 ah = ldf(TTh,  (jT * 16 + l15) * 144 + ko);
        const bf16x8 al = ldf(TTl,  (jT * 16 + l15) * 144 + ko);
        const bf16x8 bh = ldf(M2Th, (iT * 16 + l15) * 144 + ko);
        const bf16x8 bl = ldf(M2Tl, (iT * 16 + l15) * 144 + ko);
        acc = MFMA16(ah, bh, acc);
        acc = MFMA16(ah, bl, acc);
        acc = MFMA16(al, bh, acc);
      }
      const int c = iT * 16 + l15;        // col index in [0,96)
      const int j0 = jT * 16 + l4 * 4;    // row base (4-contig)
      if (jT < 4 && iT < 4) {             // Qxx block: QXX[c][j0..+3] = S + Qx
        const float4 q = ld4(Qxg + c * 64 + j0);
        float4 o; o.x = acc[0] + q.x; o.y = acc[1] + q.y;
        o.z = acc[2] + q.z; o.w = acc[3] + q.w;
        st4(QXX + c * 68 + j0, o);
      } else if (jT < 4) {                // upper-right: gXT[n][x] fp32 store
        const int n = c - 64;
        float4 o; o.x = acc[0]; o.y = acc[1]; o.z = acc[2]; o.w = acc[3];
        st4(gXT + s * 2048 + n * 64 + j0, o);
      } else if (iT < 4) {                // lower-left: QXU pack [x=c][n-quad]
        st_pack4(XUh, XUl, c * 40 + (j0 - 64), acc);
      } else {                            // Quu block: QUU[b][a0..+3] = S + Ru
        const int b = c - 64, a0 = j0 - 64;
        const float4 rv = ld4(Rug + b * 32 + a0);
        float4 o; o.x = acc[0] + rv.x; o.y = acc[1] + rv.y;
        o.z = acc[2] + rv.z; o.w = acc[3] + rv.w;
        st4(QUU + b * 36 + a0, o);
      }
    }
    __syncthreads();

    // ---- PhC: wave 0 register GJ inverse of Quu -> gQI fp32 + QI bf16 pack
    if (wv == 0) {
      const int i = lane & 31, h = lane >> 5;
      float W[16];
#pragma unroll
      for (int r = 0; r < 16; ++r) W[r] = QUU[i * 36 + h * 16 + r];
#pragma unroll
      for (int j = 0; j < 32; ++j) {
        const int jh = j >> 4, jr = j & 15;
        const float d = __shfl(W[jr], j | (jh << 5));
        const float pinv = 1.0f / d;
        const float f = __shfl(W[jr], i | (jh << 5));
        float pr[16];
#pragma unroll
        for (int r = 0; r < 16; ++r) pr[r] = __shfl(W[r], j | (h << 5));
        float nw[16];
        if (i == j) {
#pragma unroll
          for (int r = 0; r < 16; ++r) nw[r] = pr[r] * pinv;
          if (h == jh) nw[jr] = pinv;
        } else {
          const float g = f * pinv;
#pragma unroll
          for (int r = 0; r < 16; ++r) nw[r] = fmaf(-g, pr[r], W[r]);
          if (h == jh) nw[jr] = -g;
        }
#pragma unroll
        for (int r = 0; r < 16; ++r) W[r] = nw[r];
      }
#pragma unroll
      for (int q = 0; q < 4; ++q) {
        float4 o; o.x = W[4 * q]; o.y = W[4 * q + 1];
        o.z = W[4 * q + 2]; o.w = W[4 * q + 3];
        st4(gQI + s * 1024 + i * 32 + h * 16 + 4 * q, o);
        us4 hh, ll;
#pragma unroll
        for (int r = 0; r < 4; ++r) {
          const unsigned short hv = bfh(W[4 * q + r]);
          hh[r] = (short)hv;
          ll[r] = (short)bfh(W[4 * q + r] - bf2f(hv));
        }
        *(us4*)(QIh + (i * 40 + h * 16 + 4 * q) * 2) = hh;
        *(us4*)(QIl + (i * 40 + h * 16 + 4 * q) * 2) = ll;
      }
    }
    __syncthreads();

    // ---- PhD: out4 = QI * Qxu^T (8 tiles, 1/wave). gK = -out4; KT pack.
    {
      const int mT = wv & 1, xT = wv >> 1;
      f32x4 acc = {0.f, 0.f, 0.f, 0.f};
      const int ko = (l4 * 8) * 2;
      const bf16x8 ah = ldf(QIh, (mT * 16 + l15) * 80 + ko);
      const bf16x8 al = ldf(QIl, (mT * 16 + l15) * 80 + ko);
      const bf16x8 bh = ldf(XUh, (xT * 16 + l15) * 80 + ko);
      const bf16x8 bl = ldf(XUl, (xT * 16 + l15) * 80 + ko);
      acc = MFMA16(ah, bh, acc);
      acc = MFMA16(ah, bl, acc);
      acc = MFMA16(al, bh, acc);
      const int x = xT * 16 + l15, m0 = mT * 16 + l4 * 4;
#pragma unroll
      for (int r = 0; r < 4; ++r) gK[s * 2048 + (m0 + r) * 64 + x] = -acc[r];
      st_pack4(KTh, KTl, x * 40 + m0, acc);
    }
    __syncthreads();

    // publish stage s (gP[s+1] prev iter; gXT PhB; gQI PhC; gK PhD — drained)
    if (t == 0) {
      __threadfence();
      __hip_atomic_store(flags + s, 1, __ATOMIC_RELEASE, __HIP_MEMORY_SCOPE_AGENT);
    }

    // ---- PhE: P' = Qxx - Qxu*KT^T (16 tiles); write gP[s] + P pack. Skip s=0.
    if (s > 0) {
      for (int tt = wv; tt < 16; tt += 8) {
        const int iT = tt & 3, jT = tt >> 2;
        f32x4 acc = {0.f, 0.f, 0.f, 0.f};
        const int ko = (l4 * 8) * 2;
        const bf16x8 ah = ldf(XUh, (iT * 16 + l15) * 80 + ko);
        const bf16x8 al = ldf(XUl, (iT * 16 + l15) * 80 + ko);
        const bf16x8 bh = ldf(KTh, (jT * 16 + l15) * 80 + ko);
        const bf16x8 bl = ldf(KTl, (jT * 16 + l15) * 80 + ko);
        acc = MFMA16(ah, bh, acc);
        acc = MFMA16(ah, bl, acc);
        acc = MFMA16(al, bh, acc);
        const int j = jT * 16 + l15, i0 = iT * 16 + l4 * 4;
        f32x4 pv;
#pragma unroll
        for (int r = 0; r < 4; ++r) {
          pv[r] = QXX[(i0 + r) * 68 + j] - acc[r];
          gP[s * 4096 + (i0 + r) * 64 + j] = pv[r];
        }
        st_pack4(Ph, Pl, j * 72 + i0, pv);   // symmetry: Ppack[j][i] = P'[i][j]
      }
    }
    __syncthreads();
  }
}

// ---------------------------------------------------------------------------
// Consumer: per-batch residuals (threads 0-255) + wave-0 recursions, flag-gated.
// ---------------------------------------------------------------------------
DEV void consumer(float* lds, int b, const float* x0g, const float* xg,
                  const float* ug, const float* lg, const float* Ag,
                  const float* Bg, const float* Qxg, const float* Rug,
                  const float* Qfg, float* ws, float* outp) {
  const int t = threadIdx.x;
  const float* gP  = ws + WS_P;
  const float* gQI = ws + WS_QI;
  const float* gXT = ws + WS_XT;
  const float* gK  = ws + WS_K;
  const int* flags = (const int*)(ws + WS_P);

  float* sx   = lds;            // 2112 (dead after residuals)
  float* sl   = lds + 2112;     // 2112 (dead after residuals)
  float* su   = lds + 4224;     // 1024 (dead after residuals)
  float* sAT  = lds;            // overlay, stride 68
  float* xres = lds + 5248;     // 2048
  float* lxs  = lds + 7296;     // 2048
  float* lus  = lds + 9344;     // 1024
  float* kv   = lds + 10368;    // 1024
  float* swv  = lds + 11392;    // 64
  float* sqv  = lds + 11456;    // 32
  float* sduv = lds + 11488;    // 32
  float* sdxv = lds + 11520;    // 64

  for (int idx = t; idx < (NH + 1) * NX; idx += 512) {
    const int s = idx >> 6, i = idx & 63;
    sx[idx] = xg[(s * NB + b) * NX + i];
    sl[idx] = lg[(s * NB + b) * NX + i];
  }
  for (int idx = t; idx < NH * NU; idx += 512) {
    const int s = idx >> 5, j = idx & 31;
    su[idx] = ug[(s * NB + b) * NU + j];
  }
  __syncthreads();

  if (t < 256) {
    const int s = t >> 3, i0 = (t & 7) * 8;
    float accx[8], accl[8];
#pragma unroll
    for (int ii = 0; ii < 8; ++ii) {
      accx[ii] = -sx[(s + 1) * NX + i0 + ii];
      accl[ii] = -sl[s * NX + i0 + ii];
    }
#pragma unroll 2
    for (int k0 = 0; k0 < NX; k0 += 4) {
      const float4 xv = ld4(sx + s * NX + k0);
#pragma unroll
      for (int ii = 0; ii < 8; ++ii) {
        accx[ii] += dot4(ld4(Ag + (i0 + ii) * NX + k0), xv);
        accl[ii] += dot4(ld4(Qxg + (i0 + ii) * NX + k0), xv);
      }
    }
#pragma unroll 2
    for (int k0 = 0; k0 < NU; k0 += 4) {
      const float4 uv = ld4(su + s * NU + k0);
#pragma unroll
      for (int ii = 0; ii < 8; ++ii)
        accx[ii] += dot4(ld4(Bg + (i0 + ii) * NU + k0), uv);
    }
#pragma unroll 4
    for (int k = 0; k < NX; ++k) {
      const float lv = sl[(s + 1) * NX + k];
      fma8(accl, lv, ld4(Ag + k * NX + i0), ld4(Ag + k * NX + i0 + 4));
    }
#pragma unroll
    for (int ii = 0; ii < 8; ++ii) {
      xres[s * NX + i0 + ii] = accx[ii];
      lxs[s * NX + i0 + ii] = accl[ii];
    }
  }
  if (t < 256) {
    const int s = t >> 3, j0 = (t & 7) * 4;
    float4 acc = {0, 0, 0, 0};
#pragma unroll 2
    for (int k0 = 0; k0 < NU; k0 += 4) {
      const float4 uv = ld4(su + s * NU + k0);
      acc.x += dot4(ld4(Rug + (j0 + 0) * NU + k0), uv);
      acc.y += dot4(ld4(Rug + (j0 + 1) * NU + k0), uv);
      acc.z += dot4(ld4(Rug + (j0 + 2) * NU + k0), uv);
      acc.w += dot4(ld4(Rug + (j0 + 3) * NU + k0), uv);
    }
#pragma unroll 4
    for (int k = 0; k < NX; ++k) {
      const float lv = sl[(s + 1) * NX + k];
      fma4(acc, lv, ld4(Bg + k * NU + j0));
    }
    lus[s * NU + j0 + 0] = acc.x; lus[s * NU + j0 + 1] = acc.y;
    lus[s * NU + j0 + 2] = acc.z; lus[s * NU + j0 + 3] = acc.w;
  }

  float p_i = 0.0f, dx_i = 0.0f;
  if (t < 64) {
    const int i = t;
    float acc = -sl[NH * NX + i];
#pragma unroll 4
    for (int k0 = 0; k0 < NX; k0 += 4)
      acc += dot4(ld4(Qfg + i * NX + k0), ld4(sx + NH * NX + k0));
    p_i = acc;
    dx_i = x0g[b * NX + i] - sx[i];
  }
  __syncthreads();

  for (int idx = t; idx < NX * NX / 4; idx += 512) {
    const int k = idx >> 4, i4 = (idx & 15) * 4;
    const float4 a4 = ld4(Ag + k * NX + i4);
    sAT[(i4 + 0) * 68 + k] = a4.x;
    sAT[(i4 + 1) * 68 + k] = a4.y;
    sAT[(i4 + 2) * 68 + k] = a4.z;
    sAT[(i4 + 3) * 68 + k] = a4.w;
  }
  __syncthreads();

  if (t >= 64) return;   // wave 0 continues barrier-free

  const int i = t;
  const int j = t & 31;
  const int hh = t >> 5;

  for (int s = NH - 1; s >= 0; --s) {
    while (__hip_atomic_load(flags + s, __ATOMIC_ACQUIRE, __HIP_MEMORY_SCOPE_AGENT) == 0)
      __builtin_amdgcn_s_sleep(16);

    const float* Pr = gP + (s + 1) * NX * NX + i * NX;
    const float* xr = xres + s * NX;
    float w = p_i;
#pragma unroll
    for (int k0 = 0; k0 < NX; k0 += 16) {
      w += dot4(ld4(Pr + k0),      ld4(xr + k0));
      w += dot4(ld4(Pr + k0 + 4),  ld4(xr + k0 + 4));
      w += dot4(ld4(Pr + k0 + 8),  ld4(xr + k0 + 8));
      w += dot4(ld4(Pr + k0 + 12), ld4(xr + k0 + 12));
    }
    swv[i] = w;

    float qx = lxs[s * NX + i];
#pragma unroll
    for (int k0 = 0; k0 < NX; k0 += 16) {
      qx += dot4(ld4(sAT + i * 68 + k0),      ld4(swv + k0));
      qx += dot4(ld4(sAT + i * 68 + k0 + 4),  ld4(swv + k0 + 4));
      qx += dot4(ld4(sAT + i * 68 + k0 + 8),  ld4(swv + k0 + 8));
      qx += dot4(ld4(sAT + i * 68 + k0 + 12), ld4(swv + k0 + 12));
    }

    float qa = 0.0f;
    const int kb = hh * 32;
#pragma unroll 8
    for (int kk = 0; kk < 32; ++kk)
      qa = fmaf(Bg[(kb + kk) * NU + j], swv[kb + kk], qa);
    qa += __shfl_xor(qa, 32);
    const float qu = qa + lus[s * NU + j];
    if (hh == 0) sqv[j] = qu;

    const float* Qr = gQI + s * NU * NU + j * NU + hh * 16;
    float ka = dot4(ld4(Qr),      ld4(sqv + hh * 16))
             + dot4(ld4(Qr + 4),  ld4(sqv + hh * 16 + 4))
             + dot4(ld4(Qr + 8),  ld4(sqv + hh * 16 + 8))
             + dot4(ld4(Qr + 12), ld4(sqv + hh * 16 + 12));
    ka += __shfl_xor(ka, 32);
    if (hh == 0) kv[s * NU + j] = -ka;

    const float* Xs = gXT + s * NU * NX;
    float pp = qx;
#pragma unroll 8
    for (int m = 0; m < NU; ++m)
      pp = fmaf(Xs[m * NX + i], kv[s * NU + m], pp);
    p_i = pp;
  }

  sdxv[i] = dx_i;
  for (int s = 0; s < NH; ++s) {
    const float* Kr = gK + s * NU * NX + j * NX + hh * 32;
    const float* dxh = sdxv + hh * 32;
    float da = 0.0f;
#pragma unroll
    for (int k0 = 0; k0 < 32; k0 += 16) {
      da += dot4(ld4(Kr + k0),      ld4(dxh + k0));
      da += dot4(ld4(Kr + k0 + 4),  ld4(dxh + k0 + 4));
      da += dot4(ld4(Kr + k0 + 8),  ld4(dxh + k0 + 8));
      da += dot4(ld4(Kr + k0 + 12), ld4(dxh + k0 + 12));
    }
    da += __shfl_xor(da, 32);
    const float du = da + kv[s * NU + j];
    if (hh == 0) {
      const int gi = (s * NB + b) * NU + j;
      outp[gi] = ug[gi] + du;
      sduv[j] = du;
    }

    float nxv = xres[s * NX + i];
    const float* Ar = Ag + i * NX;
#pragma unroll
    for (int k0 = 0; k0 < NX; k0 += 4)
      nxv += dot4(ld4(Ar + k0), ld4(sdxv + k0));
    const float* Br = Bg + i * NU;
#pragma unroll
    for (int m0 = 0; m0 < NU; m0 += 4)
      nxv += dot4(ld4(Br + m0), ld4(sduv + m0));
    sdxv[i] = nxv;
  }
}

__global__ void k_zero(float* ws) {
  if (threadIdx.x < 64) ((int*)(ws + WS_P))[threadIdx.x] = 0;
}

__global__ __launch_bounds__(512) void k_fused(
    const float* __restrict__ x0g, const float* __restrict__ xg,
    const float* __restrict__ ug, const float* __restrict__ lg,
    const float* __restrict__ Ag, const float* __restrict__ Bg,
    const float* __restrict__ Qxg, const float* __restrict__ Rug,
    const float* __restrict__ Qfg, float* __restrict__ ws,
    float* __restrict__ outp) {
  __shared__ __align__(16) char smem[SMEMB];
  if (blockIdx.x == 0)
    producer(smem, Ag, Bg, Qxg, Rug, Qfg, ws);
  else
    consumer((float*)smem, blockIdx.x - 1, x0g, xg, ug, lg, Ag, Bg, Qxg, Rug,
             Qfg, ws, outp);
}

extern "C" void kernel_launch(void* const* d_in, const int* in_sizes, int n_in,
                              void* d_out, int out_size, void* d_ws, size_t ws_size,
                              hipStream_t stream) {
  const float* x0  = (const float*)d_in[0];
  const float* x   = (const float*)d_in[1];
  const float* u   = (const float*)d_in[2];
  const float* lmd = (const float*)d_in[3];
  const float* A   = (const float*)d_in[4];
  const float* Bm  = (const float*)d_in[5];
  const float* Qx  = (const float*)d_in[6];
  const float* Ru  = (const float*)d_in[7];
  const float* Qf  = (const float*)d_in[8];
  float* ws  = (float*)d_ws;
  float* out = (float*)d_out;

  hipLaunchKernelGGL(k_zero, dim3(1), dim3(64), 0, stream, ws);
  hipLaunchKernelGGL(k_fused, dim3(NB + 1), dim3(512), 0, stream,
                     x0, x, u, lmd, A, Bm, Qx, Ru, Qf, ws, out);
}

// Round 8
// 386.719 us; speedup vs baseline: 2.5663x; 1.1631x over previous
//
#include <hip/hip_runtime.h>

#define DEV __device__ __forceinline__

constexpr int NX = 64, NU = 32, NH = 32, NB = 192;

// workspace float offsets
constexpr int WS_P  = 0;                           // [NH+1][4096]; slot 0 -> flags
constexpr int WS_QI = WS_P  + (NH + 1) * NX * NX;  // [NH][1024]  Quu^{-1} row-major
constexpr int WS_X  = WS_QI + NH * NU * NU;        // [NH][64*32] Qxu x-major
constexpr int WS_K  = WS_X  + NH * NX * NU;        // [NH][32*64] K u-major

typedef __attribute__((ext_vector_type(8))) short bf16x8;
typedef __attribute__((ext_vector_type(4))) float f32x4;
typedef __attribute__((ext_vector_type(4))) unsigned short us4;

// producer LDS byte offsets. Big packs: 3-level bf16, row stride 72 el (144 B,
// 16B-aligned for b128). Small packs: 2-level, stride 40 el (80 B).
constexpr int LVL_M2T = 96 * 72 * 2;   // 13824
constexpr int LVL_P   = 64 * 72 * 2;   //  9216
constexpr int LVL_TT  = 96 * 72 * 2;   // 13824
constexpr int LVL_XU  = 64 * 40 * 2;   //  5120
constexpr int LVL_KT  = 64 * 40 * 2;   //  5120
constexpr int LVL_QI  = 32 * 40 * 2;   //  2560
constexpr int oM2T = 0;
constexpr int oP   = oM2T + 3 * LVL_M2T;   // 41472
constexpr int oTT  = oP   + 3 * LVL_P;     // 69120
constexpr int oXU  = oTT  + 3 * LVL_TT;    // 110592
constexpr int oKT  = oXU  + 2 * LVL_XU;    // 120832
constexpr int oQI  = oKT  + 2 * LVL_KT;    // 131072
constexpr int oQXX = oQI  + 2 * LVL_QI;    // 136192 (fp32 64x68; QUU aliases)
constexpr int SMEMB = oQXX + 64 * 68 * 4;  // 153600

DEV unsigned short bfh(float x) {
  unsigned u = __float_as_uint(x);
  return (unsigned short)((u + 0x7FFFu + ((u >> 16) & 1u)) >> 16);
}
DEV float bf2f(unsigned short h) { return __uint_as_float(((unsigned)h) << 16); }
DEV void split3(float x, unsigned short& h, unsigned short& m, unsigned short& l) {
  h = bfh(x); float r1 = x - bf2f(h);
  m = bfh(r1); float r2 = r1 - bf2f(m);
  l = bfh(r2);
}
DEV float4 ld4(const float* p) { return *reinterpret_cast<const float4*>(p); }
DEV void   st4(float* p, float4 v) { *reinterpret_cast<float4*>(p) = v; }
DEV void st4_nt(float* p, f32x4 v) {
  __builtin_nontemporal_store(v, (f32x4*)p);
}
DEV float  dot4(float4 a, float4 b) {
  return fmaf(a.x, b.x, fmaf(a.y, b.y, fmaf(a.z, b.z, a.w * b.w)));
}
DEV void fma4(float4& a, float s, float4 b) {
  a.x = fmaf(s, b.x, a.x); a.y = fmaf(s, b.y, a.y);
  a.z = fmaf(s, b.z, a.z); a.w = fmaf(s, b.w, a.w);
}
DEV void fma8(float* acc, float s, float4 b0, float4 b1) {
  acc[0] = fmaf(s, b0.x, acc[0]); acc[1] = fmaf(s, b0.y, acc[1]);
  acc[2] = fmaf(s, b0.z, acc[2]); acc[3] = fmaf(s, b0.w, acc[3]);
  acc[4] = fmaf(s, b1.x, acc[4]); acc[5] = fmaf(s, b1.y, acc[5]);
  acc[6] = fmaf(s, b1.z, acc[6]); acc[7] = fmaf(s, b1.w, acc[7]);
}

#define MFMA16(a, b, c) __builtin_amdgcn_mfma_f32_16x16x32_bf16(a, b, c, 0, 0, 0)

// 3-level x 3-level product (error ~2^-27): 6 MFMAs, small terms first.
DEV f32x4 prod33(const char* A, int ao, int LA, const char* B, int bo, int LB,
                 f32x4 acc) {
  const bf16x8 a0 = *(const bf16x8*)(A + ao);
  const bf16x8 a1 = *(const bf16x8*)(A + LA + ao);
  const bf16x8 a2 = *(const bf16x8*)(A + 2 * LA + ao);
  const bf16x8 b0 = *(const bf16x8*)(B + bo);
  const bf16x8 b1 = *(const bf16x8*)(B + LB + bo);
  const bf16x8 b2 = *(const bf16x8*)(B + 2 * LB + bo);
  acc = MFMA16(a1, b1, acc);
  acc = MFMA16(a2, b0, acc);
  acc = MFMA16(a0, b2, acc);
  acc = MFMA16(a1, b0, acc);
  acc = MFMA16(a0, b1, acc);
  acc = MFMA16(a0, b0, acc);
  return acc;
}
// 2-level x 2-level (error ~2^-18): 3 MFMAs.
DEV f32x4 prod22(const char* A, int ao, int LA, const char* B, int bo, int LB,
                 f32x4 acc) {
  const bf16x8 a0 = *(const bf16x8*)(A + ao);
  const bf16x8 a1 = *(const bf16x8*)(A + LA + ao);
  const bf16x8 b0 = *(const bf16x8*)(B + bo);
  const bf16x8 b1 = *(const bf16x8*)(B + LB + bo);
  acc = MFMA16(a1, b0, acc);
  acc = MFMA16(a0, b1, acc);
  acc = MFMA16(a0, b0, acc);
  return acc;
}
DEV void st_pack3(char* base, int lvl, int el, f32x4 v) {
  us4 h, m, l;
#pragma unroll
  for (int r = 0; r < 4; ++r) {
    unsigned short hh, mm, ll; split3(v[r], hh, mm, ll);
    h[r] = (short)hh; m[r] = (short)mm; l[r] = (short)ll;
  }
  *(us4*)(base + el * 2) = h;
  *(us4*)(base + lvl + el * 2) = m;
  *(us4*)(base + 2 * lvl + el * 2) = l;
}
DEV void st_pack2(char* base, int lvl, int el, f32x4 v) {
  us4 h, l;
#pragma unroll
  for (int r = 0; r < 4; ++r) {
    const unsigned short hh = bfh(v[r]);
    h[r] = (short)hh;
    l[r] = (short)bfh(v[r] - bf2f(hh));
  }
  *(us4*)(base + el * 2) = h;
  *(us4*)(base + lvl + el * 2) = l;
}

// ---------------------------------------------------------------------------
// Producer (block 0, 512 threads): split-bf16 MFMA Riccati recursion.
// Phases: V -> {Quu, Qxu} -> {GJ || G} -> {K || Qxx} -> publish -> P'.
// All consumer-facing stores are non-temporal (cheap release fence).
// ---------------------------------------------------------------------------
DEV void producer(char* smem, const float* Ag, const float* Bg,
                  const float* Qxg, const float* Rug, const float* Qfg,
                  float* ws) {
  const int t = threadIdx.x, lane = t & 63, wv = t >> 6;
  const int l15 = lane & 15, l4 = lane >> 4;

  char* M2T = smem + oM2T;
  char* Pp  = smem + oP;
  char* TT  = smem + oTT;
  char* XU  = smem + oXU;
  char* KT  = smem + oKT;
  char* QI  = smem + oQI;
  float* QXX = (float*)(smem + oQXX);
  float* QUU = (float*)(smem + oQXX);   // alias; live only Ph2->Ph3

  float* gP  = ws + WS_P;
  float* gQI = ws + WS_QI;
  float* gX  = ws + WS_X;
  float* gK  = ws + WS_K;
  int* flags = (int*)(ws + WS_P);       // gP slot 0 never holds P data

  // ---- static packs: M2T[j][m] = (j<64 ? A[m][j] : B[m][j-64]); P=Qf; gP[32]
  for (int idx = t; idx < 96 * 64; idx += 512) {
    const int j = idx >> 6, m = idx & 63;
    const float v = (j < 64) ? Ag[m * 64 + j] : Bg[m * 32 + (j - 64)];
    unsigned short h, mi, lo; split3(v, h, mi, lo);
    const int eo = (j * 72 + m) * 2;
    *(unsigned short*)(M2T + eo) = h;
    *(unsigned short*)(M2T + LVL_M2T + eo) = mi;
    *(unsigned short*)(M2T + 2 * LVL_M2T + eo) = lo;
  }
  for (int idx = t; idx < 64 * 64; idx += 512) {
    const int r = idx >> 6, c = idx & 63;
    const float v = Qfg[idx];
    unsigned short h, mi, lo; split3(v, h, mi, lo);
    const int eo = (r * 72 + c) * 2;
    *(unsigned short*)(Pp + eo) = h;
    *(unsigned short*)(Pp + LVL_P + eo) = mi;
    *(unsigned short*)(Pp + 2 * LVL_P + eo) = lo;
    __builtin_nontemporal_store(v, gP + 32 * 4096 + idx);
  }
  __syncthreads();

  for (int s = NH - 1; s >= 0; --s) {
    // ---- Ph1: V = P*B -> TT rows 64..95 (8 tiles, 1/wave)
    {
      const int mT = wv >> 1, jT = 4 + (wv & 1);
      f32x4 acc = {0.f, 0.f, 0.f, 0.f};
#pragma unroll
      for (int kp = 0; kp < 2; ++kp) {
        const int ao = ((mT * 16 + l15) * 72 + kp * 32 + l4 * 8) * 2;
        const int bo = ((jT * 16 + l15) * 72 + kp * 32 + l4 * 8) * 2;
        acc = prod33(Pp, ao, LVL_P, M2T, bo, LVL_M2T, acc);
      }
      st_pack3(TT, LVL_TT, (jT * 16 + l15) * 72 + mT * 16 + l4 * 4, acc);
    }
    __syncthreads();

    // ---- Ph2: waves 0-3: Quu = Ru + B^T V ; waves 4-7: Qxu -> XU pack + gX
    if (wv < 4) {
      const int uA = wv >> 1, uB = wv & 1;
      f32x4 acc = {0.f, 0.f, 0.f, 0.f};
#pragma unroll
      for (int kp = 0; kp < 2; ++kp) {
        const int ao = (((4 + uA) * 16 + l15) * 72 + kp * 32 + l4 * 8) * 2;
        const int bo = ((64 + uB * 16 + l15) * 72 + kp * 32 + l4 * 8) * 2;
        acc = prod33(TT, ao, LVL_TT, M2T, bo, LVL_M2T, acc);
      }
      const int c = uB * 16 + l15, u0 = uA * 16 + l4 * 4;  // symmetric store
      const float4 rv = ld4(Rug + c * 32 + u0);
      QUU[c * 36 + u0 + 0] = acc[0] + rv.x;
      QUU[c * 36 + u0 + 1] = acc[1] + rv.y;
      QUU[c * 36 + u0 + 2] = acc[2] + rv.z;
      QUU[c * 36 + u0 + 3] = acc[3] + rv.w;
    } else {
      for (int q = wv - 4; q < 8; q += 4) {
        const int uT = q & 1, xT = q >> 1;
        f32x4 acc = {0.f, 0.f, 0.f, 0.f};
#pragma unroll
        for (int kp = 0; kp < 2; ++kp) {
          const int ao = (((4 + uT) * 16 + l15) * 72 + kp * 32 + l4 * 8) * 2;
          const int bo = ((xT * 16 + l15) * 72 + kp * 32 + l4 * 8) * 2;
          acc = prod33(TT, ao, LVL_TT, M2T, bo, LVL_M2T, acc);
        }
        const int x = xT * 16 + l15, u0 = uT * 16 + l4 * 4;
        st_pack2(XU, LVL_XU, x * 40 + u0, acc);
        st4_nt(gX + s * 2048 + x * 32 + u0, acc);
      }
    }
    __syncthreads();

    // ---- Ph3: wave 0 register GJ inverse of Quu ; waves 1-7: G = P*A
    if (wv == 0) {
      const int i = lane & 31, h = lane >> 5;
      float W[16];
#pragma unroll
      for (int r = 0; r < 16; ++r) W[r] = QUU[i * 36 + h * 16 + r];
#pragma unroll
      for (int j = 0; j < 32; ++j) {
        const int jh = j >> 4, jr = j & 15;
        const float d = __shfl(W[jr], j | (jh << 5));
        const float pinv = 1.0f / d;
        const float f = __shfl(W[jr], i | (jh << 5));
        float pr[16];
#pragma unroll
        for (int r = 0; r < 16; ++r) pr[r] = __shfl(W[r], j | (h << 5));
        float nw[16];
        if (i == j) {
#pragma unroll
          for (int r = 0; r < 16; ++r) nw[r] = pr[r] * pinv;
          if (h == jh) nw[jr] = pinv;
        } else {
          const float g = f * pinv;
#pragma unroll
          for (int r = 0; r < 16; ++r) nw[r] = fmaf(-g, pr[r], W[r]);
          if (h == jh) nw[jr] = -g;
        }
#pragma unroll
        for (int r = 0; r < 16; ++r) W[r] = nw[r];
      }
#pragma unroll
      for (int q = 0; q < 4; ++q) {
        f32x4 o = {W[4 * q], W[4 * q + 1], W[4 * q + 2], W[4 * q + 3]};
        st4_nt(gQI + s * 1024 + i * 32 + h * 16 + 4 * q, o);
        us4 hh, ll;
#pragma unroll
        for (int r = 0; r < 4; ++r) {
          const unsigned short hv = bfh(W[4 * q + r]);
          hh[r] = (short)hv;
          ll[r] = (short)bfh(W[4 * q + r] - bf2f(hv));
        }
        *(us4*)(QI + (i * 40 + h * 16 + 4 * q) * 2) = hh;
        *(us4*)(QI + LVL_QI + (i * 40 + h * 16 + 4 * q) * 2) = ll;
      }
    } else {
      for (int tt = wv - 1; tt < 16; tt += 7) {
        const int mT = tt & 3, jT = tt >> 2;
        f32x4 acc = {0.f, 0.f, 0.f, 0.f};
#pragma unroll
        for (int kp = 0; kp < 2; ++kp) {
          const int ao = ((mT * 16 + l15) * 72 + kp * 32 + l4 * 8) * 2;
          const int bo = ((jT * 16 + l15) * 72 + kp * 32 + l4 * 8) * 2;
          acc = prod33(Pp, ao, LVL_P, M2T, bo, LVL_M2T, acc);
        }
        st_pack3(TT, LVL_TT, (jT * 16 + l15) * 72 + mT * 16 + l4 * 4, acc);
      }
    }
    __syncthreads();

    // ---- Ph4: waves 0-1: K = QI*Qxu^T (gK = -val) ; waves 2-7: Qxx
    if (wv < 2) {
      for (int tt = wv; tt < 8; tt += 2) {
        const int mT = tt & 1, xT = tt >> 1;
        f32x4 acc = {0.f, 0.f, 0.f, 0.f};
        const int ao = ((mT * 16 + l15) * 40 + l4 * 8) * 2;
        const int bo = ((xT * 16 + l15) * 40 + l4 * 8) * 2;
        acc = prod22(QI, ao, LVL_QI, XU, bo, LVL_XU, acc);
        const int x = xT * 16 + l15, m0 = mT * 16 + l4 * 4;
#pragma unroll
        for (int r = 0; r < 4; ++r)
          __builtin_nontemporal_store(-acc[r], gK + s * 2048 + (m0 + r) * 64 + x);
        st_pack2(KT, LVL_KT, x * 40 + m0, acc);
      }
    } else {
      for (int tt = wv - 2; tt < 16; tt += 6) {
        const int jT = tt >> 2, iT = tt & 3;
        f32x4 acc = {0.f, 0.f, 0.f, 0.f};
#pragma unroll
        for (int kp = 0; kp < 2; ++kp) {
          const int ao = ((jT * 16 + l15) * 72 + kp * 32 + l4 * 8) * 2;
          const int bo = ((iT * 16 + l15) * 72 + kp * 32 + l4 * 8) * 2;
          acc = prod33(TT, ao, LVL_TT, M2T, bo, LVL_M2T, acc);
        }
        const int c = iT * 16 + l15, j0 = jT * 16 + l4 * 4;  // symmetric store
        const float4 q = ld4(Qxg + c * 64 + j0);
        QXX[c * 68 + j0 + 0] = acc[0] + q.x;
        QXX[c * 68 + j0 + 1] = acc[1] + q.y;
        QXX[c * 68 + j0 + 2] = acc[2] + q.z;
        QXX[c * 68 + j0 + 3] = acc[3] + q.w;
      }
    }
    __syncthreads();

    // publish stage s (gP[s+1] prior Ph5; gX Ph2; gQI Ph3; gK Ph4 — drained)
    if (t == 0) {
      __threadfence();
      __hip_atomic_store(flags + s, 1, __ATOMIC_RELEASE, __HIP_MEMORY_SCOPE_AGENT);
    }

    // ---- Ph5: P' = Qxx - Qxu*(QI Qxu^T) ; gP[s] NT + P pack3. Skip s=0.
    if (s > 0) {
      for (int tt = wv; tt < 16; tt += 8) {
        const int iT = tt & 3, jT = tt >> 2;
        f32x4 acc = {0.f, 0.f, 0.f, 0.f};
        const int ao = ((iT * 16 + l15) * 40 + l4 * 8) * 2;
        const int bo = ((jT * 16 + l15) * 40 + l4 * 8) * 2;
        acc = prod22(XU, ao, LVL_XU, KT, bo, LVL_KT, acc);
        const int j = jT * 16 + l15, i0 = iT * 16 + l4 * 4;
        f32x4 pv;
#pragma unroll
        for (int r = 0; r < 4; ++r) {
          pv[r] = QXX[(i0 + r) * 68 + j] - acc[r];
          __builtin_nontemporal_store(pv[r], gP + s * 4096 + (i0 + r) * 64 + j);
        }
        st_pack3(Pp, LVL_P, j * 72 + i0, pv);  // symmetry: pack[j][i]=P'[i][j]
      }
    }
    __syncthreads();
  }
}

// ---------------------------------------------------------------------------
// Consumer: per-batch residuals (threads 0-255) + wave-0 recursions.
// Relaxed polls + single acquire per stage; coalesced gX reads.
// ---------------------------------------------------------------------------
DEV void consumer(float* lds, int b, const float* x0g, const float* xg,
                  const float* ug, const float* lg, const float* Ag,
                  const float* Bg, const float* Qxg, const float* Rug,
                  const float* Qfg, float* ws, float* outp) {
  const int t = threadIdx.x;
  const float* gP  = ws + WS_P;
  const float* gQI = ws + WS_QI;
  const float* gX  = ws + WS_X;
  const float* gK  = ws + WS_K;
  int* flags = (int*)(ws + WS_P);

  float* sx   = lds;            // 2112 (dead after residuals)
  float* sl   = lds + 2112;     // 2112 (dead after residuals)
  float* su   = lds + 4224;     // 1024 (dead after residuals)
  float* sAT  = lds;            // overlay, stride 68
  float* xres = lds + 5248;     // 2048
  float* lxs  = lds + 7296;     // 2048
  float* lus  = lds + 9344;     // 1024
  float* kv   = lds + 10368;    // 1024
  float* swv  = lds + 11392;    // 64
  float* sqv  = lds + 11456;    // 32
  float* sduv = lds + 11488;    // 32
  float* sdxv = lds + 11520;    // 64

  for (int idx = t; idx < (NH + 1) * NX; idx += 512) {
    const int s = idx >> 6, i = idx & 63;
    sx[idx] = xg[(s * NB + b) * NX + i];
    sl[idx] = lg[(s * NB + b) * NX + i];
  }
  for (int idx = t; idx < NH * NU; idx += 512) {
    const int s = idx >> 5, j = idx & 31;
    su[idx] = ug[(s * NB + b) * NU + j];
  }
  __syncthreads();

  if (t < 256) {
    const int s = t >> 3, i0 = (t & 7) * 8;
    float accx[8], accl[8];
#pragma unroll
    for (int ii = 0; ii < 8; ++ii) {
      accx[ii] = -sx[(s + 1) * NX + i0 + ii];
      accl[ii] = -sl[s * NX + i0 + ii];
    }
#pragma unroll 2
    for (int k0 = 0; k0 < NX; k0 += 4) {
      const float4 xv = ld4(sx + s * NX + k0);
#pragma unroll
      for (int ii = 0; ii < 8; ++ii) {
        accx[ii] += dot4(ld4(Ag + (i0 + ii) * NX + k0), xv);
        accl[ii] += dot4(ld4(Qxg + (i0 + ii) * NX + k0), xv);
      }
    }
#pragma unroll 2
    for (int k0 = 0; k0 < NU; k0 += 4) {
      const float4 uv = ld4(su + s * NU + k0);
#pragma unroll
      for (int ii = 0; ii < 8; ++ii)
        accx[ii] += dot4(ld4(Bg + (i0 + ii) * NU + k0), uv);
    }
#pragma unroll 4
    for (int k = 0; k < NX; ++k) {
      const float lv = sl[(s + 1) * NX + k];
      fma8(accl, lv, ld4(Ag + k * NX + i0), ld4(Ag + k * NX + i0 + 4));
    }
#pragma unroll
    for (int ii = 0; ii < 8; ++ii) {
      xres[s * NX + i0 + ii] = accx[ii];
      lxs[s * NX + i0 + ii] = accl[ii];
    }
  }
  if (t < 256) {
    const int s = t >> 3, j0 = (t & 7) * 4;
    float4 acc = {0, 0, 0, 0};
#pragma unroll 2
    for (int k0 = 0; k0 < NU; k0 += 4) {
      const float4 uv = ld4(su + s * NU + k0);
      acc.x += dot4(ld4(Rug + (j0 + 0) * NU + k0), uv);
      acc.y += dot4(ld4(Rug + (j0 + 1) * NU + k0), uv);
      acc.z += dot4(ld4(Rug + (j0 + 2) * NU + k0), uv);
      acc.w += dot4(ld4(Rug + (j0 + 3) * NU + k0), uv);
    }
#pragma unroll 4
    for (int k = 0; k < NX; ++k) {
      const float lv = sl[(s + 1) * NX + k];
      fma4(acc, lv, ld4(Bg + k * NU + j0));
    }
    lus[s * NU + j0 + 0] = acc.x; lus[s * NU + j0 + 1] = acc.y;
    lus[s * NU + j0 + 2] = acc.z; lus[s * NU + j0 + 3] = acc.w;
  }

  float p_i = 0.0f, dx_i = 0.0f;
  if (t < 64) {
    const int i = t;
    float acc = -sl[NH * NX + i];
#pragma unroll 4
    for (int k0 = 0; k0 < NX; k0 += 4)
      acc += dot4(ld4(Qfg + i * NX + k0), ld4(sx + NH * NX + k0));
    p_i = acc;
    dx_i = x0g[b * NX + i] - sx[i];
  }
  __syncthreads();

  for (int idx = t; idx < NX * NX / 4; idx += 512) {
    const int k = idx >> 4, i4 = (idx & 15) * 4;
    const float4 a4 = ld4(Ag + k * NX + i4);
    sAT[(i4 + 0) * 68 + k] = a4.x;
    sAT[(i4 + 1) * 68 + k] = a4.y;
    sAT[(i4 + 2) * 68 + k] = a4.z;
    sAT[(i4 + 3) * 68 + k] = a4.w;
  }
  __syncthreads();

  if (t >= 64) return;   // wave 0 continues barrier-free

  const int i = t;
  const int j = t & 31;
  const int hh = t >> 5;

  for (int s = NH - 1; s >= 0; --s) {
    // relaxed poll; single acquire on success
    while (__hip_atomic_load(flags + s, __ATOMIC_RELAXED,
                             __HIP_MEMORY_SCOPE_AGENT) == 0)
      __builtin_amdgcn_s_sleep(4);
    (void)__hip_atomic_load(flags + s, __ATOMIC_ACQUIRE,
                            __HIP_MEMORY_SCOPE_AGENT);

    const float* Pr = gP + (s + 1) * NX * NX + i * NX;
    const float* xr = xres + s * NX;
    float w = p_i;
#pragma unroll
    for (int k0 = 0; k0 < NX; k0 += 16) {
      w += dot4(ld4(Pr + k0),      ld4(xr + k0));
      w += dot4(ld4(Pr + k0 + 4),  ld4(xr + k0 + 4));
      w += dot4(ld4(Pr + k0 + 8),  ld4(xr + k0 + 8));
      w += dot4(ld4(Pr + k0 + 12), ld4(xr + k0 + 12));
    }
    swv[i] = w;

    float qx = lxs[s * NX + i];
#pragma unroll
    for (int k0 = 0; k0 < NX; k0 += 16) {
      qx += dot4(ld4(sAT + i * 68 + k0),      ld4(swv + k0));
      qx += dot4(ld4(sAT + i * 68 + k0 + 4),  ld4(swv + k0 + 4));
      qx += dot4(ld4(sAT + i * 68 + k0 + 8),  ld4(swv + k0 + 8));
      qx += dot4(ld4(sAT + i * 68 + k0 + 12), ld4(swv + k0 + 12));
    }

    float qa = 0.0f;
    const int kb = hh * 32;
#pragma unroll 8
    for (int kk = 0; kk < 32; ++kk)
      qa = fmaf(Bg[(kb + kk) * NU + j], swv[kb + kk], qa);
    qa += __shfl_xor(qa, 32);
    const float qu = qa + lus[s * NU + j];
    if (hh == 0) sqv[j] = qu;

    const float* Qr = gQI + s * NU * NU + j * NU + hh * 16;
    float ka = dot4(ld4(Qr),      ld4(sqv + hh * 16))
             + dot4(ld4(Qr + 4),  ld4(sqv + hh * 16 + 4))
             + dot4(ld4(Qr + 8),  ld4(sqv + hh * 16 + 8))
             + dot4(ld4(Qr + 12), ld4(sqv + hh * 16 + 12));
    ka += __shfl_xor(ka, 32);
    if (hh == 0) kv[s * NU + j] = -ka;

    // p = qx + Qxu k   (gX x-major: lane i reads 32 contiguous floats)
    const float* Xs = gX + s * 2048 + i * 32;
    float pp = qx;
#pragma unroll
    for (int m0 = 0; m0 < NU; m0 += 4)
      pp += dot4(ld4(Xs + m0), ld4(kv + s * NU + m0));
    p_i = pp;
  }

  sdxv[i] = dx_i;
  for (int s = 0; s < NH; ++s) {
    const float* Kr = gK + s * NU * NX + j * NX + hh * 32;
    const float* dxh = sdxv + hh * 32;
    float da = 0.0f;
#pragma unroll
    for (int k0 = 0; k0 < 32; k0 += 16) {
      da += dot4(ld4(Kr + k0),      ld4(dxh + k0));
      da += dot4(ld4(Kr + k0 + 4),  ld4(dxh + k0 + 4));
      da += dot4(ld4(Kr + k0 + 8),  ld4(dxh + k0 + 8));
      da += dot4(ld4(Kr + k0 + 12), ld4(dxh + k0 + 12));
    }
    da += __shfl_xor(da, 32);
    const float du = da + kv[s * NU + j];
    if (hh == 0) {
      const int gi = (s * NB + b) * NU + j;
      outp[gi] = ug[gi] + du;
      sduv[j] = du;
    }

    float nxv = xres[s * NX + i];
    const float* Ar = Ag + i * NX;
#pragma unroll
    for (int k0 = 0; k0 < NX; k0 += 4)
      nxv += dot4(ld4(Ar + k0), ld4(sdxv + k0));
    const float* Br = Bg + i * NU;
#pragma unroll
    for (int m0 = 0; m0 < NU; m0 += 4)
      nxv += dot4(ld4(Br + m0), ld4(sduv + m0));
    sdxv[i] = nxv;
  }
}

__global__ void k_zero(float* ws) {
  if (threadIdx.x < 64) ((int*)(ws + WS_P))[threadIdx.x] = 0;
}

__global__ __launch_bounds__(512) void k_fused(
    const float* __restrict__ x0g, const float* __restrict__ xg,
    const float* __restrict__ ug, const float* __restrict__ lg,
    const float* __restrict__ Ag, const float* __restrict__ Bg,
    const float* __restrict__ Qxg, const float* __restrict__ Rug,
    const float* __restrict__ Qfg, float* __restrict__ ws,
    float* __restrict__ outp) {
  __shared__ __align__(16) char smem[SMEMB];
  if (blockIdx.x == 0)
    producer(smem, Ag, Bg, Qxg, Rug, Qfg, ws);
  else
    consumer((float*)smem, blockIdx.x - 1, x0g, xg, ug, lg, Ag, Bg, Qxg, Rug,
             Qfg, ws, outp);
}

extern "C" void kernel_launch(void* const* d_in, const int* in_sizes, int n_in,
                              void* d_out, int out_size, void* d_ws, size_t ws_size,
                              hipStream_t stream) {
  const float* x0  = (const float*)d_in[0];
  const float* x   = (const float*)d_in[1];
  const float* u   = (const float*)d_in[2];
  const float* lmd = (const float*)d_in[3];
  const float* A   = (const float*)d_in[4];
  const float* Bm  = (const float*)d_in[5];
  const float* Qx  = (const float*)d_in[6];
  const float* Ru  = (const float*)d_in[7];
  const float* Qf  = (const float*)d_in[8];
  float* ws  = (float*)d_ws;
  float* out = (float*)d_out;

  hipLaunchKernelGGL(k_zero, dim3(1), dim3(64), 0, stream, ws);
  hipLaunchKernelGGL(k_fused, dim3(NB + 1), dim3(512), 0, stream,
                     x0, x, u, lmd, A, Bm, Qx, Ru, Qf, ws, out);
}